// Round 8
// baseline (4341.237 us; speedup 1.0000x reference)
//
#include <hip/hip_runtime.h>
#include <hip/hip_bf16.h>
#include <float.h>
#include <math.h>
#include <stdint.h>

constexpr int B_   = 8;
constexpr int N_   = 785;
constexpr int C_   = 768;
constexpr int H_   = 12;
constexpr int DH_  = 64;
constexpr int NT_  = 393;
constexpr int QKVC = 3 * C_;   // 2304
constexpr int BN   = B_ * N_;  // 6280
constexpr int BT   = B_ * NT_; // 3144
constexpr int MSEL = N_ - 1;   // 784
constexpr float  SCALE_F = 0.125f;
constexpr double LNEPS   = 1e-5;
constexpr double SMEPS   = 1e-6;

#define DEV static __device__ __forceinline__

typedef __hip_bfloat16 bf16;

DEV float b2f(bf16 v) { return __bfloat162float(v); }

// ---------------- dtype detection + canonicalization ----------------
__global__ void detect_kernel(const uint32_t* __restrict__ n1w, int* __restrict__ flag) {
  if (threadIdx.x == 0 && blockIdx.x == 0)
    *flag = (n1w[0] == 0x3F803F80u) ? 1 : 0;
}

__global__ __launch_bounds__(256) void convert_kernel(
    const void* __restrict__ src, float* __restrict__ dst, int n,
    const int* __restrict__ flag) {
  int isb = *flag;
  int i = blockIdx.x * 256 + threadIdx.x;
  int stride = gridDim.x * 256;
  if (isb) {
    const bf16* s = (const bf16*)src;
    for (; i < n; i += stride) dst[i] = b2f(s[i]);
  } else {
    const float* s = (const float*)src;
    for (; i < n; i += stride) dst[i] = s[i];
  }
}

// ---------------- block reductions ----------------
DEV double blockReduceSumD(double v, double* scratch, int nw) {
#pragma unroll
  for (int o = 32; o; o >>= 1) v += __shfl_xor(v, o);
  int lane = threadIdx.x & 63, wid = threadIdx.x >> 6;
  __syncthreads();
  if (lane == 0) scratch[wid] = v;
  __syncthreads();
  double r = scratch[0];
  for (int i = 1; i < nw; i++) r += scratch[i];
  return r;
}
DEV double blockReduceMaxD(double v, double* scratch, int nw) {
#pragma unroll
  for (int o = 32; o; o >>= 1) v = fmax(v, __shfl_xor(v, o));
  int lane = threadIdx.x & 63, wid = threadIdx.x >> 6;
  __syncthreads();
  if (lane == 0) scratch[wid] = v;
  __syncthreads();
  double r = scratch[0];
  for (int i = 1; i < nw; i++) r = fmax(r, scratch[i]);
  return r;
}
DEV float blockReduceSumF(float v, float* scratch, int nw) {
#pragma unroll
  for (int o = 32; o; o >>= 1) v += __shfl_xor(v, o);
  int lane = threadIdx.x & 63, wid = threadIdx.x >> 6;
  __syncthreads();
  if (lane == 0) scratch[wid] = v;
  __syncthreads();
  float r = scratch[0];
  for (int i = 1; i < nw; i++) r += scratch[i];
  return r;
}
DEV float blockReduceMaxF(float v, float* scratch, int nw) {
#pragma unroll
  for (int o = 32; o; o >>= 1) v = fmaxf(v, __shfl_xor(v, o));
  int lane = threadIdx.x & 63, wid = threadIdx.x >> 6;
  __syncthreads();
  if (lane == 0) scratch[wid] = v;
  __syncthreads();
  float r = scratch[0];
  for (int i = 1; i < nw; i++) r = fmaxf(r, scratch[i]);
  return r;
}

// ---------------- LN1: x(f32) -> xn64 (fp64) ----------------
__global__ __launch_bounds__(256) void ln1_kernel(
    const float* __restrict__ x, const float* __restrict__ w, const float* __restrict__ b,
    double* __restrict__ xn64) {
  int row = blockIdx.x;
  int t = threadIdx.x;
  __shared__ double scr[8];
  const float* xr = x + (size_t)row * C_;
  double vals[3];
#pragma unroll
  for (int i = 0; i < 3; i++) vals[i] = (double)xr[t + i * 256];
  double s = vals[0] + vals[1] + vals[2];
  s = blockReduceSumD(s, scr, 4);
  double mean = s / (double)C_;
  double vs = 0.0;
#pragma unroll
  for (int i = 0; i < 3; i++) { double d = vals[i] - mean; vs += d * d; }
  vs = blockReduceSumD(vs, scr, 4);
  double inv = 1.0 / sqrt(vs / (double)C_ + LNEPS);
#pragma unroll
  for (int i = 0; i < 3; i++) {
    int c = t + i * 256;
    xn64[(size_t)row * C_ + c] = (vals[i] - mean) * inv * (double)w[c] + (double)b[c];
  }
}

// ---------------- fp64 GEMM: qkv64 = xn64 @ W * rowscale; also emits fp32 cast ----
__global__ __launch_bounds__(256) void gemm_f64(
    const double* __restrict__ A, const float* __restrict__ W,
    double* __restrict__ C64, float* __restrict__ C32,
    const float* __restrict__ rowscale, int M, int K, int Ncols) {
  __shared__ double As[16][65];
  __shared__ double Bs[16][65];
  int t = threadIdx.x;
  int n0 = blockIdx.x * 64;
  int m0 = blockIdx.y * 64;
  int tm = (t >> 4) << 2, tn = (t & 15) << 2;
  double acc[4][4] = {};
  int lm = t >> 2;
  int lk = (t & 3) << 2;
  bool mvalid = (m0 + lm) < M;
  for (int k0 = 0; k0 < K; k0 += 16) {
    double a0 = 0, a1 = 0, a2 = 0, a3 = 0;
    if (mvalid) {
      const double* ap = A + (size_t)(m0 + lm) * K + k0 + lk;
      a0 = ap[0]; a1 = ap[1]; a2 = ap[2]; a3 = ap[3];
    }
    As[lk + 0][lm] = a0; As[lk + 1][lm] = a1;
    As[lk + 2][lm] = a2; As[lk + 3][lm] = a3;
#pragma unroll
    for (int i = 0; i < 4; i++) {
      int idx = t + i * 256;
      int n = idx & 63, k = idx >> 6;
      Bs[k][n] = (double)W[(size_t)(k0 + k) * Ncols + n0 + n];
    }
    __syncthreads();
#pragma unroll
    for (int k = 0; k < 16; k++) {
      double x0 = As[k][tm + 0], x1 = As[k][tm + 1], x2 = As[k][tm + 2], x3 = As[k][tm + 3];
      double y0 = Bs[k][tn + 0], y1 = Bs[k][tn + 1], y2 = Bs[k][tn + 2], y3 = Bs[k][tn + 3];
      acc[0][0] += x0 * y0; acc[0][1] += x0 * y1; acc[0][2] += x0 * y2; acc[0][3] += x0 * y3;
      acc[1][0] += x1 * y0; acc[1][1] += x1 * y1; acc[1][2] += x1 * y2; acc[1][3] += x1 * y3;
      acc[2][0] += x2 * y0; acc[2][1] += x2 * y1; acc[2][2] += x2 * y2; acc[2][3] += x2 * y3;
      acc[3][0] += x3 * y0; acc[3][1] += x3 * y1; acc[3][2] += x3 * y2; acc[3][3] += x3 * y3;
    }
    __syncthreads();
  }
#pragma unroll
  for (int i = 0; i < 4; i++) {
    int m = m0 + tm + i;
    if (m >= M) continue;
    double rs = (double)rowscale[m];
#pragma unroll
    for (int j = 0; j < 4; j++) {
      int n = n0 + tn + j;
      double v = acc[i][j] * rs;
      C64[(size_t)m * Ncols + n] = v;
      C32[(size_t)m * Ncols + n] = (float)v;
    }
  }
}

// ---------------- row-0 logits fp64 ----------------
__global__ __launch_bounds__(256) void logits0_kernel(
    const double* __restrict__ qkv64, double* __restrict__ l64) {
  int bh = blockIdx.x;
  int b = bh / H_, h = bh % H_;
  int t = threadIdx.x;
  __shared__ double qh[DH_];
  if (t < DH_) qh[t] = qkv64[(size_t)(b * N_) * QKVC + h * DH_ + t];
  __syncthreads();
  for (int n = t; n < N_; n += 256) {
    const double* kp = qkv64 + (size_t)(b * N_ + n) * QKVC + C_ + h * DH_;
    double a = 0.0;
#pragma unroll 8
    for (int d = 0; d < DH_; d++) a += qh[d] * kp[d];
    l64[(size_t)bh * N_ + n] = 0.125 * a;
  }
}

// ---------------- ||v||^2 fp64 ----------------
__global__ __launch_bounds__(256) void vnorm2_kernel(
    const double* __restrict__ qkv64, double* __restrict__ vnorm2) {
  int row = blockIdx.x;
  int t = threadIdx.x;
  __shared__ double scr[8];
  const double* vp = qkv64 + (size_t)row * QKVC + 2 * C_;
  double p = 0.0;
  for (int d = t; d < C_; d += 256) { double v = vp[d]; p += v * v; }
  double s = blockReduceSumD(p, scr, 4);
  if (t == 0) vnorm2[row] = s;
}

// ---------------- row-0 softmax fp64 (in place) ----------------
__global__ __launch_bounds__(256) void softmax0_kernel(
    double* __restrict__ l64, const float* __restrict__ policy) {
  int bh = blockIdx.x;
  int b = bh / H_;
  double* lp = l64 + (size_t)bh * N_;
  __shared__ double scr[8];
  int t = threadIdx.x;
  double mx = -1e300;
  for (int n = t; n < N_; n += 256) mx = fmax(mx, lp[n]);
  mx = blockReduceMaxD(mx, scr, 4);
  double ssum = 0.0;
  for (int n = t; n < N_; n += 256) {
    double pol = (double)policy[b * N_ + n];
    double w = (n == 0) ? 1.0 : pol;
    double e = exp(lp[n] - mx) * w;
    lp[n] = e;
    ssum += e;
  }
  ssum = blockReduceSumD(ssum, scr, 4);
  double denom = ssum + SMEPS;
  double addc = SMEPS / (double)N_;
  for (int n = t; n < N_; n += 256) lp[n] = (lp[n] + addc) / denom;
}

// ---------------- selection fp64, paranoid-simple ----------------
__global__ __launch_bounds__(1024) void select_kernel(
    const double* __restrict__ p0, const double* __restrict__ vnorm2,
    int* __restrict__ selidx, float* __restrict__ poln, float* __restrict__ out_pol) {
  int b = blockIdx.x;
  int t = threadIdx.x;
  __shared__ double sigv[MSEL];
  __shared__ double svals[MSEL];
  __shared__ double nc[MSEL];
  __shared__ int    ord[MSEL];
  __shared__ int    pick[MSEL];
  __shared__ int    spick[MSEL];
  __shared__ int    uq[MSEL];
  __shared__ int    suq[MSEL];
  __shared__ double sh_ys;

  if (t < MSEL) {
    int n = t + 1;
    double s = 0.0;
#pragma unroll
    for (int h = 0; h < H_; h++) s += p0[(size_t)(b * H_ + h) * N_ + n];
    sigv[t] = s * sqrt(vnorm2[b * N_ + n]);
  }
  __syncthreads();
  // stable ascending rank-sort (normalization cancels in ncdf)
  if (t < MSEL) {
    double v = sigv[t];
    int rank = 0;
    for (int i = 0; i < MSEL; i++) {
      double vi = sigv[i];
      rank += (vi < v) || (vi == v && i < t);
    }
    ord[rank] = t;
    svals[rank] = v;
  }
  __syncthreads();
  if (t == 0) {
    double a = 0.0;
    for (int i = 0; i < MSEL; i++) { a += svals[i]; svals[i] = a; }
  }
  __syncthreads();
  {
    double c0 = svals[0], cN = svals[MSEL - 1];
    if (t < MSEL) nc[t] = (svals[t] - c0) / (cN - c0);
  }
  __syncthreads();
  if (t == 0) {
    double m = 1e300;
    for (int i = 0; i < MSEL; i++) {
      double v = nc[i];
      if (v == 0.0) v += 100000000.0;
      m = fmin(m, v);
    }
    sh_ys = m;
  }
  __syncthreads();
  if (t < MSEL) {
    double s = sh_ys;
    double ysj = (t == MSEL - 1) ? 1.0 : (double)t / 783.0;
    double y = s + (ysj * 783.0 - s * (double)t) / 783.0;
    double bd = 1e300;
    int bi = 0;
    for (int i = 0; i < MSEL; i++) {
      double d = fabs(y - nc[i]);
      if (d < bd) { bd = d; bi = i; }
    }
    pick[t] = bi;
  }
  __syncthreads();
  if (t < MSEL) {
    int p = pick[t];
    int rank = 0;
    for (int i = 0; i < MSEL; i++) {
      int pi = pick[i];
      rank += (pi < p) || (pi == p && i < t);
    }
    spick[rank] = p;
  }
  __syncthreads();
  if (t < MSEL) {
    int s = spick[t];
    int nxt = (t < MSEL - 1) ? spick[t + 1] : 1;
    uq[t] = (nxt == s) ? MSEL : s;
  }
  __syncthreads();
  if (t < MSEL) {
    int u = uq[t];
    int rank = 0;
    for (int i = 0; i < MSEL; i++) {
      int ui = uq[i];
      rank += (ui < u) || (ui == u && i < t);
    }
    suq[rank] = u;
  }
  __syncthreads();
  if (t < NT_) {
    int sel, polI;
    if (t == 0) { sel = 0; polI = 1; }
    else {
      int ut = suq[t - 1];
      polI = (ut != MSEL) ? 1 : 0;
      sel = polI ? (ord[ut] + 1) : -1;
    }
    selidx[b * NT_ + t] = sel;
    poln[b * NT_ + t] = (float)polI;
    out_pol[b * NT_ + t] = (float)polI;   // fp32 output
  }
}

// ---------------- value path (fp32) ----------------
__global__ __launch_bounds__(256) void attn_kernel(
    const float* __restrict__ qkv, const int* __restrict__ selidx,
    const float* __restrict__ policy, float* __restrict__ attn_out) {
  int row = blockIdx.x;
  int b = row / NT_;
  int t = threadIdx.x;
  __shared__ float qL[C_];
  __shared__ float sc[H_][801];
  __shared__ float fscr[8];
  int r = selidx[row];
  float* orow = attn_out + (size_t)row * C_;
  if (r < 0) {
    for (int i = t; i < C_; i += 256) orow[i] = 0.f;
    return;
  }
  const float* qr = qkv + (size_t)(b * N_ + r) * QKVC;
  for (int i = t; i < C_; i += 256) qL[i] = qr[i];
  __syncthreads();
  int lane = t & 63, team = t >> 6;
  for (int n = team; n < N_; n += 4) {
    const float* kr = qkv + (size_t)(b * N_ + n) * QKVC + C_;
    float s[H_];
#pragma unroll
    for (int h = 0; h < H_; h++) s[h] = qL[h * 64 + lane] * kr[h * 64 + lane];
#pragma unroll
    for (int o = 32; o; o >>= 1) {
#pragma unroll
      for (int h = 0; h < H_; h++) s[h] += __shfl_xor(s[h], o);
    }
    if (lane < H_) sc[lane][n] = s[lane] * SCALE_F;
  }
  __syncthreads();
  for (int h = 0; h < H_; h++) {
    float m = -1e30f;
    for (int n = t; n < N_; n += 256) m = fmaxf(m, sc[h][n]);
    m = blockReduceMaxF(m, fscr, 4);
    float p = 0.f;
    for (int n = t; n < N_; n += 256) {
      float pol = policy[b * N_ + n];
      float w = (n == r) ? 1.0f : pol;
      float e = expf(sc[h][n] - m) * w;
      sc[h][n] = e;
      p += e;
    }
    float S = blockReduceSumF(p, fscr, 4);
    float denom = S + 1e-6f;
    float addc = 1e-6f / (float)N_;
    for (int n = t; n < N_; n += 256) sc[h][n] = (sc[h][n] + addc) / denom;
  }
  __syncthreads();
  for (int cc = 0; cc < 3; cc++) {
    int c = t + cc * 256;
    int h = c >> 6;
    float acc = 0.f;
    const float* vcol = qkv + (size_t)(b * N_) * QKVC + 2 * C_ + c;
    for (int n = 0; n < N_; n++) acc += sc[h][n] * vcol[(size_t)n * QKVC];
    orow[c] = acc;
  }
}

__global__ __launch_bounds__(256) void gemm_f32(
    const float* __restrict__ A, const float* __restrict__ W, float* __restrict__ Cc,
    const float* __restrict__ bias, int M, int K, int Ncols) {
  __shared__ float As[16][68];
  __shared__ float Bs[16][68];
  int t = threadIdx.x;
  int n0 = blockIdx.x * 64;
  int m0 = blockIdx.y * 64;
  int tm = (t >> 4) << 2, tn = (t & 15) << 2;
  float acc[4][4] = {{0.f}};
  int lm = t >> 2;
  int lk = (t & 3) << 2;
  bool mvalid = (m0 + lm) < M;
  for (int k0 = 0; k0 < K; k0 += 16) {
    float4 av = make_float4(0.f, 0.f, 0.f, 0.f);
    if (mvalid) av = *(const float4*)(A + (size_t)(m0 + lm) * K + k0 + lk);
    As[lk + 0][lm] = av.x; As[lk + 1][lm] = av.y;
    As[lk + 2][lm] = av.z; As[lk + 3][lm] = av.w;
#pragma unroll
    for (int i = 0; i < 4; i++) {
      int idx = t + i * 256;
      int n = idx & 63, k = idx >> 6;
      Bs[k][n] = W[(size_t)(k0 + k) * Ncols + n0 + n];
    }
    __syncthreads();
#pragma unroll
    for (int k = 0; k < 16; k++) {
      float a0 = As[k][tm + 0], a1 = As[k][tm + 1], a2 = As[k][tm + 2], a3 = As[k][tm + 3];
      float b0 = Bs[k][tn + 0], b1 = Bs[k][tn + 1], b2 = Bs[k][tn + 2], b3 = Bs[k][tn + 3];
      acc[0][0] += a0 * b0; acc[0][1] += a0 * b1; acc[0][2] += a0 * b2; acc[0][3] += a0 * b3;
      acc[1][0] += a1 * b0; acc[1][1] += a1 * b1; acc[1][2] += a1 * b2; acc[1][3] += a1 * b3;
      acc[2][0] += a2 * b0; acc[2][1] += a2 * b1; acc[2][2] += a2 * b2; acc[2][3] += a2 * b3;
      acc[3][0] += a3 * b0; acc[3][1] += a3 * b1; acc[3][2] += a3 * b2; acc[3][3] += a3 * b3;
    }
    __syncthreads();
  }
#pragma unroll
  for (int i = 0; i < 4; i++) {
    int m = m0 + tm + i;
    if (m >= M) continue;
#pragma unroll
    for (int j = 0; j < 4; j++) {
      int n = n0 + tn + j;
      float v = acc[i][j];
      if (bias) v += bias[n];
      Cc[(size_t)m * Ncols + n] = v;
    }
  }
}

__global__ __launch_bounds__(256) void e2_kernel(
    const float* __restrict__ cbuf, const float* __restrict__ poln,
    const int* __restrict__ selidx, const float* __restrict__ x, float* __restrict__ x2) {
  int row = blockIdx.x;
  int t = threadIdx.x;
  int b = row / NT_;
  int r = selidx[row];
  float pn = poln[row];
  for (int i = t; i < C_; i += 256) {
    float sx = (r >= 0) ? x[(size_t)(b * N_ + r) * C_ + i] : 0.f;
    x2[(size_t)row * C_ + i] = sx + cbuf[(size_t)row * C_ + i] * pn;
  }
}

__global__ __launch_bounds__(256) void ln2_kernel(
    const float* __restrict__ xin, const float* __restrict__ w, const float* __restrict__ b,
    float* __restrict__ xout) {
  int row = blockIdx.x;
  int t = threadIdx.x;
  __shared__ float scr[8];
  const float* xr = xin + (size_t)row * C_;
  float vals[3];
#pragma unroll
  for (int i = 0; i < 3; i++) vals[i] = xr[t + i * 256];
  float s = vals[0] + vals[1] + vals[2];
  s = blockReduceSumF(s, scr, 4);
  float mean = s / (float)C_;
  float vs = 0.f;
#pragma unroll
  for (int i = 0; i < 3; i++) { float d = vals[i] - mean; vs += d * d; }
  vs = blockReduceSumF(vs, scr, 4);
  float sd = sqrtf(vs / (float)C_ + 1e-5f);
#pragma unroll
  for (int i = 0; i < 3; i++) {
    int c = t + i * 256;
    xout[(size_t)row * C_ + c] = (vals[i] - mean) / sd * w[c] + b[c];
  }
}

DEV float gelu_exact(float v) { return 0.5f * v * (1.0f + erff(v * 0.70710678118654752f)); }

__global__ __launch_bounds__(256) void gelu_kernel(float* __restrict__ h) {
  size_t i = (size_t)blockIdx.x * 256 + threadIdx.x;
  float4 v = ((float4*)h)[i];
  v.x = gelu_exact(v.x); v.y = gelu_exact(v.y);
  v.z = gelu_exact(v.z); v.w = gelu_exact(v.w);
  ((float4*)h)[i] = v;
}

__global__ __launch_bounds__(256) void e4_kernel(
    const float* __restrict__ x2, const float* __restrict__ cbuf,
    const float* __restrict__ poln, float* __restrict__ out) {
  int row = blockIdx.x;
  int t = threadIdx.x;
  float pn = poln[row];
  for (int i = t; i < C_; i += 256) {
    float v = x2[(size_t)row * C_ + i] + cbuf[(size_t)row * C_ + i] * pn;
    out[(size_t)row * C_ + i] = v;   // fp32 output
  }
}

// ---------------- launcher ----------------
extern "C" void kernel_launch(void* const* d_in, const int* in_sizes, int n_in,
                              void* d_out, int out_size, void* d_ws, size_t ws_size,
                              hipStream_t stream) {
  char* ws = (char*)d_ws;
  size_t off = 0;
  auto alloc = [&](size_t bytes) {
    size_t o = off;
    off += (bytes + 255) & ~(size_t)255;
    return o;
  };

  int*   flag   = (int*)(ws + alloc(256));
  float* cx     = (float*)(ws + alloc((size_t)BN * C_ * 4));
  float* cpol   = (float*)(ws + alloc((size_t)BN * 4));
  float* cn1w   = (float*)(ws + alloc((size_t)C_ * 4));
  float* cn1b   = (float*)(ws + alloc((size_t)C_ * 4));
  float* cqkvw  = (float*)(ws + alloc((size_t)C_ * QKVC * 4));
  float* cprojw = (float*)(ws + alloc((size_t)C_ * C_ * 4));
  float* cprojb = (float*)(ws + alloc((size_t)C_ * 4));
  float* cn2w   = (float*)(ws + alloc((size_t)C_ * 4));
  float* cn2b   = (float*)(ws + alloc((size_t)C_ * 4));
  float* cfc1w  = (float*)(ws + alloc((size_t)C_ * 4 * C_ * 4));
  float* cfc1b  = (float*)(ws + alloc((size_t)4 * C_ * 4));
  float* cfc2w  = (float*)(ws + alloc((size_t)4 * C_ * C_ * 4));
  float* cfc2b  = (float*)(ws + alloc((size_t)C_ * 4));

  double* xn64   = (double*)(ws + alloc((size_t)BN * C_ * 8));
  float*  qkv32  = (float*)(ws + alloc((size_t)BN * QKVC * 4));
  double* vnorm2 = (double*)(ws + alloc((size_t)BN * 8));
  double* l64    = (double*)(ws + alloc((size_t)B_ * H_ * N_ * 8));
  int*    selidx = (int*)(ws + alloc((size_t)BT * 4));
  float*  poln   = (float*)(ws + alloc((size_t)BT * 4));

  // UNION: qkv64 (dead after select) overlaps late-stage fp32 buffers.
  size_t qkv64_bytes = (size_t)BN * QKVC * 8;
  size_t late_step   = ((size_t)BT * C_ * 4 + 255) & ~(size_t)255;
  size_t late_bytes  = late_step * 4 + (size_t)BT * 4 * C_ * 4;
  size_t union_bytes = qkv64_bytes > late_bytes ? qkv64_bytes : late_bytes;
  char*  ub     = ws + alloc(union_bytes);
  double* qkv64  = (double*)ub;
  float*  attn_o = (float*)(ub);
  float*  cbuf   = (float*)(ub + late_step * 1);
  float*  x2     = (float*)(ub + late_step * 2);
  float*  xn2    = (float*)(ub + late_step * 3);
  float*  h32    = (float*)(ub + late_step * 4);
  if (off > ws_size) return;

  float* out_x = (float*)d_out;   // fp32 outputs
  float* out_p = out_x + (size_t)BT * C_;

  detect_kernel<<<1, 64, 0, stream>>>((const uint32_t*)d_in[2], flag);

  struct { const void* src; float* dst; int n; } conv[13] = {
    {d_in[0],  cx,     BN * C_},
    {d_in[1],  cpol,   BN},
    {d_in[2],  cn1w,   C_},
    {d_in[3],  cn1b,   C_},
    {d_in[4],  cqkvw,  C_ * QKVC},
    {d_in[5],  cprojw, C_ * C_},
    {d_in[6],  cprojb, C_},
    {d_in[7],  cn2w,   C_},
    {d_in[8],  cn2b,   C_},
    {d_in[9],  cfc1w,  C_ * 4 * C_},
    {d_in[10], cfc1b,  4 * C_},
    {d_in[11], cfc2w,  4 * C_ * C_},
    {d_in[12], cfc2b,  C_},
  };
  for (int i = 0; i < 13; i++) {
    int blocks = (conv[i].n + 255) / 256;
    if (blocks > 4096) blocks = 4096;
    convert_kernel<<<blocks, 256, 0, stream>>>(conv[i].src, conv[i].dst, conv[i].n, flag);
  }

  // fp64 scoring pipeline
  ln1_kernel<<<BN, 256, 0, stream>>>(cx, cn1w, cn1b, xn64);
  {
    dim3 g(QKVC / 64, (BN + 63) / 64);
    gemm_f64<<<g, 256, 0, stream>>>(xn64, cqkvw, qkv64, qkv32, cpol, BN, C_, QKVC);
  }
  logits0_kernel<<<B_ * H_, 256, 0, stream>>>(qkv64, l64);
  vnorm2_kernel<<<BN, 256, 0, stream>>>(qkv64, vnorm2);
  softmax0_kernel<<<B_ * H_, 256, 0, stream>>>(l64, cpol);
  select_kernel<<<B_, 1024, 0, stream>>>(l64, vnorm2, selidx, poln, out_p);

  // value path (qkv64 dead; union region reused)
  attn_kernel<<<BT, 256, 0, stream>>>(qkv32, selidx, cpol, attn_o);
  {
    dim3 g(C_ / 64, (BT + 63) / 64);
    gemm_f32<<<g, 256, 0, stream>>>(attn_o, cprojw, cbuf, cprojb, BT, C_, C_);
  }
  e2_kernel<<<BT, 256, 0, stream>>>(cbuf, poln, selidx, cx, x2);
  ln2_kernel<<<BT, 256, 0, stream>>>(x2, cn2w, cn2b, xn2);
  {
    dim3 g(4 * C_ / 64, (BT + 63) / 64);
    gemm_f32<<<g, 256, 0, stream>>>(xn2, cfc1w, h32, cfc1b, BT, C_, 4 * C_);
  }
  gelu_kernel<<<(BT * 4 * C_) / 1024, 256, 0, stream>>>(h32);
  {
    dim3 g(C_ / 64, (BT + 63) / 64);
    gemm_f32<<<g, 256, 0, stream>>>(h32, cfc2w, cbuf, cfc2b, BT, 4 * C_, C_);
  }
  e4_kernel<<<BT, 256, 0, stream>>>(x2, cbuf, poln, out_x);
}

// Round 9
// 3999.126 us; speedup vs baseline: 1.0855x; 1.0855x over previous
//
#include <hip/hip_runtime.h>
#include <hip/hip_bf16.h>
#include <float.h>
#include <math.h>
#include <stdint.h>

constexpr int B_   = 8;
constexpr int N_   = 785;
constexpr int C_   = 768;
constexpr int H_   = 12;
constexpr int DH_  = 64;
constexpr int NT_  = 393;
constexpr int QKVC = 3 * C_;   // 2304
constexpr int BN   = B_ * N_;  // 6280
constexpr int BT   = B_ * NT_; // 3144
constexpr int MSEL = N_ - 1;   // 784
constexpr float  SCALE_F = 0.125f;
constexpr double LNEPS   = 1e-5;
constexpr double SMEPS   = 1e-6;

#define DEV static __device__ __forceinline__

typedef __hip_bfloat16 bf16;

// ---------------- block reductions ----------------
DEV double blockReduceSumD(double v, double* scratch, int nw) {
#pragma unroll
  for (int o = 32; o; o >>= 1) v += __shfl_xor(v, o);
  int lane = threadIdx.x & 63, wid = threadIdx.x >> 6;
  __syncthreads();
  if (lane == 0) scratch[wid] = v;
  __syncthreads();
  double r = scratch[0];
  for (int i = 1; i < nw; i++) r += scratch[i];
  return r;
}
DEV double blockReduceMaxD(double v, double* scratch, int nw) {
#pragma unroll
  for (int o = 32; o; o >>= 1) v = fmax(v, __shfl_xor(v, o));
  int lane = threadIdx.x & 63, wid = threadIdx.x >> 6;
  __syncthreads();
  if (lane == 0) scratch[wid] = v;
  __syncthreads();
  double r = scratch[0];
  for (int i = 1; i < nw; i++) r = fmax(r, scratch[i]);
  return r;
}
DEV float blockReduceSumF(float v, float* scratch, int nw) {
#pragma unroll
  for (int o = 32; o; o >>= 1) v += __shfl_xor(v, o);
  int lane = threadIdx.x & 63, wid = threadIdx.x >> 6;
  __syncthreads();
  if (lane == 0) scratch[wid] = v;
  __syncthreads();
  float r = scratch[0];
  for (int i = 1; i < nw; i++) r += scratch[i];
  return r;
}
DEV float blockReduceMaxF(float v, float* scratch, int nw) {
#pragma unroll
  for (int o = 32; o; o >>= 1) v = fmaxf(v, __shfl_xor(v, o));
  int lane = threadIdx.x & 63, wid = threadIdx.x >> 6;
  __syncthreads();
  if (lane == 0) scratch[wid] = v;
  __syncthreads();
  float r = scratch[0];
  for (int i = 1; i < nw; i++) r = fmaxf(r, scratch[i]);
  return r;
}

// ---------------- LN1: x(f32) -> xn64 (fp64 scoring) + xn32 (fp32 value) ----------
__global__ __launch_bounds__(256) void ln1_kernel(
    const float* __restrict__ x, const float* __restrict__ w, const float* __restrict__ b,
    double* __restrict__ xn64, float* __restrict__ xn32) {
  int row = blockIdx.x;
  int t = threadIdx.x;
  __shared__ double scr[8];
  const float* xr = x + (size_t)row * C_;
  double vals[3];
#pragma unroll
  for (int i = 0; i < 3; i++) vals[i] = (double)xr[t + i * 256];
  double s = vals[0] + vals[1] + vals[2];
  s = blockReduceSumD(s, scr, 4);
  double mean = s / (double)C_;
  double vs = 0.0;
#pragma unroll
  for (int i = 0; i < 3; i++) { double d = vals[i] - mean; vs += d * d; }
  vs = blockReduceSumD(vs, scr, 4);
  double inv = 1.0 / sqrt(vs / (double)C_ + LNEPS);
#pragma unroll
  for (int i = 0; i < 3; i++) {
    int c = t + i * 256;
    double o = (vals[i] - mean) * inv * (double)w[c] + (double)b[c];
    xn64[(size_t)row * C_ + c] = o;
    xn32[(size_t)row * C_ + c] = (float)o;
  }
}

// ---------------- fp32 GEMM: C = A[MxK] @ W[KxN] (+bias)(*rowscale) ----------------
__global__ __launch_bounds__(256) void gemm_f32(
    const float* __restrict__ A, const float* __restrict__ W, float* __restrict__ Cc,
    const float* __restrict__ bias, const float* __restrict__ rowscale,
    int M, int K, int Ncols) {
  __shared__ float As[16][68];
  __shared__ float Bs[16][68];
  int t = threadIdx.x;
  int n0 = blockIdx.x * 64;
  int m0 = blockIdx.y * 64;
  int tm = (t >> 4) << 2, tn = (t & 15) << 2;
  float acc[4][4] = {{0.f}};
  int lm = t >> 2;
  int lk = (t & 3) << 2;
  bool mvalid = (m0 + lm) < M;
  for (int k0 = 0; k0 < K; k0 += 16) {
    float4 av = make_float4(0.f, 0.f, 0.f, 0.f);
    if (mvalid) av = *(const float4*)(A + (size_t)(m0 + lm) * K + k0 + lk);
    As[lk + 0][lm] = av.x; As[lk + 1][lm] = av.y;
    As[lk + 2][lm] = av.z; As[lk + 3][lm] = av.w;
#pragma unroll
    for (int i = 0; i < 4; i++) {
      int idx = t + i * 256;
      int n = idx & 63, k = idx >> 6;
      Bs[k][n] = W[(size_t)(k0 + k) * Ncols + n0 + n];
    }
    __syncthreads();
#pragma unroll
    for (int k = 0; k < 16; k++) {
      float a0 = As[k][tm + 0], a1 = As[k][tm + 1], a2 = As[k][tm + 2], a3 = As[k][tm + 3];
      float b0 = Bs[k][tn + 0], b1 = Bs[k][tn + 1], b2 = Bs[k][tn + 2], b3 = Bs[k][tn + 3];
      acc[0][0] += a0 * b0; acc[0][1] += a0 * b1; acc[0][2] += a0 * b2; acc[0][3] += a0 * b3;
      acc[1][0] += a1 * b0; acc[1][1] += a1 * b1; acc[1][2] += a1 * b2; acc[1][3] += a1 * b3;
      acc[2][0] += a2 * b0; acc[2][1] += a2 * b1; acc[2][2] += a2 * b2; acc[2][3] += a2 * b3;
      acc[3][0] += a3 * b0; acc[3][1] += a3 * b1; acc[3][2] += a3 * b2; acc[3][3] += a3 * b3;
    }
    __syncthreads();
  }
#pragma unroll
  for (int i = 0; i < 4; i++) {
    int m = m0 + tm + i;
    if (m >= M) continue;
    float rs = rowscale ? rowscale[m] : 1.0f;
#pragma unroll
    for (int j = 0; j < 4; j++) {
      int n = n0 + tn + j;
      float v = acc[i][j];
      if (bias) v += bias[n];
      Cc[(size_t)m * Ncols + n] = v * rs;
    }
  }
}

// ---------------- q0 (row-0 query, fp64): q0[b][j] = pol0 * <xn0, Wq[:,j]> --------
__global__ __launch_bounds__(256) void q0_kernel(
    const double* __restrict__ xn64, const float* __restrict__ qkvw,
    const float* __restrict__ policy, double* __restrict__ q064) {
  int b = blockIdx.x;
  int t = threadIdx.x;
  __shared__ double x0[C_];
  for (int i = t; i < C_; i += 256) x0[i] = xn64[(size_t)(b * N_) * C_ + i];
  __syncthreads();
  double pol = (double)policy[b * N_];
  for (int j = t; j < C_; j += 256) {
    double a = 0.0;
    for (int c = 0; c < C_; c++) a += x0[c] * (double)qkvw[(size_t)c * QKVC + j];
    q064[b * C_ + j] = a * pol;
  }
}

// ---------------- g[b,h,c] = sum_d q0[b,h*64+d] * Wk[c, h*64+d]  (fp64) ----------
__global__ __launch_bounds__(256) void g_kernel(
    const double* __restrict__ q064, const float* __restrict__ qkvw,
    double* __restrict__ g64) {
  int bh = blockIdx.x;
  int b = bh / H_, h = bh % H_;
  int t = threadIdx.x;
  __shared__ double qh[DH_];
  if (t < DH_) qh[t] = q064[b * C_ + h * DH_ + t];
  __syncthreads();
  for (int c = t; c < C_; c += 256) {
    const float* wp = qkvw + (size_t)c * QKVC + C_ + h * DH_;
    double a = 0.0;
#pragma unroll 8
    for (int d = 0; d < DH_; d++) a += qh[d] * (double)wp[d];
    g64[(size_t)bh * C_ + c] = a;
  }
}

// ---------------- row-0 logits fp64: l[b,h,n] = 0.125 * pol_n * <xn_n, g_bh> -----
__global__ __launch_bounds__(256) void logits_kernel(
    const double* __restrict__ xn64, const double* __restrict__ g64,
    const float* __restrict__ policy, double* __restrict__ l64) {
  int row = blockIdx.x;
  int b = row / N_;
  int n = row % N_;
  int t = threadIdx.x;
  __shared__ double xr[C_];
  __shared__ double scr[8];
  for (int i = t; i < C_; i += 256) xr[i] = xn64[(size_t)row * C_ + i];
  __syncthreads();
  double pol = (double)policy[row];
  for (int h = 0; h < H_; h++) {
    const double* gp = g64 + (size_t)(b * H_ + h) * C_;
    double p = 0.0;
    for (int i = t; i < C_; i += 256) p += xr[i] * gp[i];
    double s = blockReduceSumD(p, scr, 4);
    if (t == 0) l64[(size_t)(b * H_ + h) * N_ + n] = 0.125 * pol * s;
  }
}

// ---------------- ||v||^2 fp64 (staged row-block; pol^2 baked in) -----------------
__global__ __launch_bounds__(256) void vnorm_kernel(
    const double* __restrict__ xn64, const float* __restrict__ qkvw,
    const float* __restrict__ policy, double* __restrict__ vnorm2) {
  __shared__ double xr[8][C_];  // 49152 B
  __shared__ double scr[8];
  int r0 = blockIdx.x * 8;
  int t = threadIdx.x;
  for (int i = t; i < 8 * C_; i += 256)
    xr[i / C_][i % C_] = xn64[(size_t)(r0 + i / C_) * C_ + (i % C_)];
  __syncthreads();
  double acc[8][3] = {};
  for (int c = 0; c < C_; c++) {
    const float* wp = qkvw + (size_t)c * QKVC + 2 * C_;
    double w0 = (double)wp[t];
    double w1 = (double)wp[t + 256];
    double w2 = (double)wp[t + 512];
#pragma unroll
    for (int r = 0; r < 8; r++) {
      double xv = xr[r][c];
      acc[r][0] += xv * w0; acc[r][1] += xv * w1; acc[r][2] += xv * w2;
    }
  }
  for (int r = 0; r < 8; r++) {
    double p = acc[r][0] * acc[r][0] + acc[r][1] * acc[r][1] + acc[r][2] * acc[r][2];
    double s = blockReduceSumD(p, scr, 4);
    if (t == 0) {
      double pol = (double)policy[r0 + r];
      vnorm2[r0 + r] = s * pol * pol;
    }
  }
}

// ---------------- row-0 softmax fp64 (in place l64 -> p0) ----------------
__global__ __launch_bounds__(256) void softmax0_kernel(
    double* __restrict__ l64, const float* __restrict__ policy) {
  int bh = blockIdx.x;
  int b = bh / H_;
  double* lp = l64 + (size_t)bh * N_;
  __shared__ double scr[8];
  int t = threadIdx.x;
  double mx = -1e300;
  for (int n = t; n < N_; n += 256) mx = fmax(mx, lp[n]);
  mx = blockReduceMaxD(mx, scr, 4);
  double ssum = 0.0;
  for (int n = t; n < N_; n += 256) {
    double pol = (double)policy[b * N_ + n];
    double w = (n == 0) ? 1.0 : pol;
    double e = exp(lp[n] - mx) * w;
    lp[n] = e;
    ssum += e;
  }
  ssum = blockReduceSumD(ssum, scr, 4);
  double denom = ssum + SMEPS;
  double addc = SMEPS / (double)N_;
  for (int n = t; n < N_; n += 256) lp[n] = (lp[n] + addc) / denom;
}

// ---------------- selection fp64, paranoid-simple ----------------
__global__ __launch_bounds__(1024) void select_kernel(
    const double* __restrict__ p0, const double* __restrict__ vnorm2,
    int* __restrict__ selidx, float* __restrict__ poln, float* __restrict__ out_pol) {
  int b = blockIdx.x;
  int t = threadIdx.x;
  __shared__ double sigv[MSEL];
  __shared__ double svals[MSEL];
  __shared__ double nc[MSEL];
  __shared__ int    ord[MSEL];
  __shared__ int    pick[MSEL];
  __shared__ int    spick[MSEL];
  __shared__ int    uq[MSEL];
  __shared__ int    suq[MSEL];
  __shared__ double sh_ys;

  if (t < MSEL) {
    int n = t + 1;
    double s = 0.0;
#pragma unroll
    for (int h = 0; h < H_; h++) s += p0[(size_t)(b * H_ + h) * N_ + n];
    sigv[t] = s * sqrt(vnorm2[b * N_ + n]);
  }
  __syncthreads();
  if (t < MSEL) {
    double v = sigv[t];
    int rank = 0;
    for (int i = 0; i < MSEL; i++) {
      double vi = sigv[i];
      rank += (vi < v) || (vi == v && i < t);
    }
    ord[rank] = t;
    svals[rank] = v;
  }
  __syncthreads();
  if (t == 0) {
    double a = 0.0;
    for (int i = 0; i < MSEL; i++) { a += svals[i]; svals[i] = a; }
  }
  __syncthreads();
  {
    double c0 = svals[0], cN = svals[MSEL - 1];
    if (t < MSEL) nc[t] = (svals[t] - c0) / (cN - c0);
  }
  __syncthreads();
  if (t == 0) {
    double m = 1e300;
    for (int i = 0; i < MSEL; i++) {
      double v = nc[i];
      if (v == 0.0) v += 100000000.0;
      m = fmin(m, v);
    }
    sh_ys = m;
  }
  __syncthreads();
  if (t < MSEL) {
    double s = sh_ys;
    double ysj = (t == MSEL - 1) ? 1.0 : (double)t / 783.0;
    double y = s + (ysj * 783.0 - s * (double)t) / 783.0;
    double bd = 1e300;
    int bi = 0;
    for (int i = 0; i < MSEL; i++) {
      double d = fabs(y - nc[i]);
      if (d < bd) { bd = d; bi = i; }
    }
    pick[t] = bi;
  }
  __syncthreads();
  if (t < MSEL) {
    int p = pick[t];
    int rank = 0;
    for (int i = 0; i < MSEL; i++) {
      int pi = pick[i];
      rank += (pi < p) || (pi == p && i < t);
    }
    spick[rank] = p;
  }
  __syncthreads();
  if (t < MSEL) {
    int s = spick[t];
    int nxt = (t < MSEL - 1) ? spick[t + 1] : 1;
    uq[t] = (nxt == s) ? MSEL : s;
  }
  __syncthreads();
  if (t < MSEL) {
    int u = uq[t];
    int rank = 0;
    for (int i = 0; i < MSEL; i++) {
      int ui = uq[i];
      rank += (ui < u) || (ui == u && i < t);
    }
    suq[rank] = u;
  }
  __syncthreads();
  if (t < NT_) {
    int sel, polI;
    if (t == 0) { sel = 0; polI = 1; }
    else {
      int ut = suq[t - 1];
      polI = (ut != MSEL) ? 1 : 0;
      sel = polI ? (ord[ut] + 1) : -1;
    }
    selidx[b * NT_ + t] = sel;
    poln[b * NT_ + t] = (float)polI;
    out_pol[b * NT_ + t] = (float)polI;
  }
}

// ---------------- value path (fp32) ----------------
__global__ __launch_bounds__(256) void attn_kernel(
    const float* __restrict__ qkv, const int* __restrict__ selidx,
    const float* __restrict__ policy, float* __restrict__ attn_out) {
  int row = blockIdx.x;
  int b = row / NT_;
  int t = threadIdx.x;
  __shared__ float qL[C_];
  __shared__ float sc[H_][801];
  __shared__ float fscr[8];
  int r = selidx[row];
  float* orow = attn_out + (size_t)row * C_;
  if (r < 0) {
    for (int i = t; i < C_; i += 256) orow[i] = 0.f;
    return;
  }
  const float* qr = qkv + (size_t)(b * N_ + r) * QKVC;
  for (int i = t; i < C_; i += 256) qL[i] = qr[i];
  __syncthreads();
  int lane = t & 63, team = t >> 6;
  for (int n = team; n < N_; n += 4) {
    const float* kr = qkv + (size_t)(b * N_ + n) * QKVC + C_;
    float s[H_];
#pragma unroll
    for (int h = 0; h < H_; h++) s[h] = qL[h * 64 + lane] * kr[h * 64 + lane];
#pragma unroll
    for (int o = 32; o; o >>= 1) {
#pragma unroll
      for (int h = 0; h < H_; h++) s[h] += __shfl_xor(s[h], o);
    }
    if (lane < H_) sc[lane][n] = s[lane] * SCALE_F;
  }
  __syncthreads();
  for (int h = 0; h < H_; h++) {
    float m = -1e30f;
    for (int n = t; n < N_; n += 256) m = fmaxf(m, sc[h][n]);
    m = blockReduceMaxF(m, fscr, 4);
    float p = 0.f;
    for (int n = t; n < N_; n += 256) {
      float pol = policy[b * N_ + n];
      float w = (n == r) ? 1.0f : pol;
      float e = expf(sc[h][n] - m) * w;
      sc[h][n] = e;
      p += e;
    }
    float S = blockReduceSumF(p, fscr, 4);
    float denom = S + 1e-6f;
    float addc = 1e-6f / (float)N_;
    for (int n = t; n < N_; n += 256) sc[h][n] = (sc[h][n] + addc) / denom;
  }
  __syncthreads();
  for (int cc = 0; cc < 3; cc++) {
    int c = t + cc * 256;
    int h = c >> 6;
    float acc = 0.f;
    const float* vcol = qkv + (size_t)(b * N_) * QKVC + 2 * C_ + c;
    for (int n = 0; n < N_; n++) acc += sc[h][n] * vcol[(size_t)n * QKVC];
    orow[c] = acc;
  }
}

__global__ __launch_bounds__(256) void e2_kernel(
    const float* __restrict__ cbuf, const float* __restrict__ poln,
    const int* __restrict__ selidx, const float* __restrict__ x, float* __restrict__ x2) {
  int row = blockIdx.x;
  int t = threadIdx.x;
  int b = row / NT_;
  int r = selidx[row];
  float pn = poln[row];
  for (int i = t; i < C_; i += 256) {
    float sx = (r >= 0) ? x[(size_t)(b * N_ + r) * C_ + i] : 0.f;
    x2[(size_t)row * C_ + i] = sx + cbuf[(size_t)row * C_ + i] * pn;
  }
}

__global__ __launch_bounds__(256) void ln2_kernel(
    const float* __restrict__ xin, const float* __restrict__ w, const float* __restrict__ b,
    float* __restrict__ xout) {
  int row = blockIdx.x;
  int t = threadIdx.x;
  __shared__ float scr[8];
  const float* xr = xin + (size_t)row * C_;
  float vals[3];
#pragma unroll
  for (int i = 0; i < 3; i++) vals[i] = xr[t + i * 256];
  float s = vals[0] + vals[1] + vals[2];
  s = blockReduceSumF(s, scr, 4);
  float mean = s / (float)C_;
  float vs = 0.f;
#pragma unroll
  for (int i = 0; i < 3; i++) { float d = vals[i] - mean; vs += d * d; }
  vs = blockReduceSumF(vs, scr, 4);
  float sd = sqrtf(vs / (float)C_ + 1e-5f);
#pragma unroll
  for (int i = 0; i < 3; i++) {
    int c = t + i * 256;
    xout[(size_t)row * C_ + c] = (vals[i] - mean) / sd * w[c] + b[c];
  }
}

DEV float gelu_exact(float v) { return 0.5f * v * (1.0f + erff(v * 0.70710678118654752f)); }

__global__ __launch_bounds__(256) void gelu_kernel(float* __restrict__ h) {
  size_t i = (size_t)blockIdx.x * 256 + threadIdx.x;
  float4 v = ((float4*)h)[i];
  v.x = gelu_exact(v.x); v.y = gelu_exact(v.y);
  v.z = gelu_exact(v.z); v.w = gelu_exact(v.w);
  ((float4*)h)[i] = v;
}

__global__ __launch_bounds__(256) void e4_kernel(
    const float* __restrict__ x2, const float* __restrict__ cbuf,
    const float* __restrict__ poln, float* __restrict__ out) {
  int row = blockIdx.x;
  int t = threadIdx.x;
  float pn = poln[row];
  for (int i = t; i < C_; i += 256) {
    float v = x2[(size_t)row * C_ + i] + cbuf[(size_t)row * C_ + i] * pn;
    out[(size_t)row * C_ + i] = v;
  }
}

// ---------------- launcher ----------------
extern "C" void kernel_launch(void* const* d_in, const int* in_sizes, int n_in,
                              void* d_out, int out_size, void* d_ws, size_t ws_size,
                              hipStream_t stream) {
  // inputs are fp32 (established R1/R7/R8); use directly, no conversion
  const float* x      = (const float*)d_in[0];
  const float* policy = (const float*)d_in[1];
  const float* n1w    = (const float*)d_in[2];
  const float* n1b    = (const float*)d_in[3];
  const float* qkvw   = (const float*)d_in[4];
  const float* projw  = (const float*)d_in[5];
  const float* projb  = (const float*)d_in[6];
  const float* n2w    = (const float*)d_in[7];
  const float* n2b    = (const float*)d_in[8];
  const float* fc1w   = (const float*)d_in[9];
  const float* fc1b   = (const float*)d_in[10];
  const float* fc2w   = (const float*)d_in[11];
  const float* fc2b   = (const float*)d_in[12];

  char* ws = (char*)d_ws;
  size_t off = 0;
  auto alloc = [&](size_t bytes) {
    size_t o = off;
    off += (bytes + 255) & ~(size_t)255;
    return o;
  };

  double* xn64   = (double*)(ws + alloc((size_t)BN * C_ * 8));
  float*  xn32   = (float*)(ws + alloc((size_t)BN * C_ * 4));
  float*  qkv32  = (float*)(ws + alloc((size_t)BN * QKVC * 4));
  double* vnorm2 = (double*)(ws + alloc((size_t)BN * 8));
  double* q064   = (double*)(ws + alloc((size_t)B_ * C_ * 8));
  double* g64    = (double*)(ws + alloc((size_t)B_ * H_ * C_ * 8));
  double* l64    = (double*)(ws + alloc((size_t)B_ * H_ * N_ * 8));
  int*    selidx = (int*)(ws + alloc((size_t)BT * 4));
  float*  poln   = (float*)(ws + alloc((size_t)BT * 4));
  float*  attn_o = (float*)(ws + alloc((size_t)BT * C_ * 4));
  float*  cbuf   = (float*)(ws + alloc((size_t)BT * C_ * 4));
  float*  x2     = (float*)(ws + alloc((size_t)BT * C_ * 4));
  float*  xn2    = (float*)(ws + alloc((size_t)BT * C_ * 4));
  float*  h32    = (float*)(ws + alloc((size_t)BT * 4 * C_ * 4));
  if (off > ws_size) return;

  float* out_x = (float*)d_out;   // fp32 outputs
  float* out_p = out_x + (size_t)BT * C_;

  ln1_kernel<<<BN, 256, 0, stream>>>(x, n1w, n1b, xn64, xn32);

  // value-path qkv (fp32 GEMM with policy rowscale)
  {
    dim3 g(QKVC / 64, (BN + 63) / 64);
    gemm_f32<<<g, 256, 0, stream>>>(xn32, qkvw, qkv32, nullptr, policy, BN, C_, QKVC);
  }

  // fp64 scoring path (factorized; no qkv64 materialization)
  q0_kernel<<<B_, 256, 0, stream>>>(xn64, qkvw, policy, q064);
  g_kernel<<<B_ * H_, 256, 0, stream>>>(q064, qkvw, g64);
  logits_kernel<<<BN, 256, 0, stream>>>(xn64, g64, policy, l64);
  vnorm_kernel<<<BN / 8, 256, 0, stream>>>(xn64, qkvw, policy, vnorm2);
  softmax0_kernel<<<B_ * H_, 256, 0, stream>>>(l64, policy);
  select_kernel<<<B_, 1024, 0, stream>>>(l64, vnorm2, selidx, poln, out_p);

  // value path
  attn_kernel<<<BT, 256, 0, stream>>>(qkv32, selidx, policy, attn_o);
  {
    dim3 g(C_ / 64, (BT + 63) / 64);
    gemm_f32<<<g, 256, 0, stream>>>(attn_o, projw, cbuf, projb, nullptr, BT, C_, C_);
  }
  e2_kernel<<<BT, 256, 0, stream>>>(cbuf, poln, selidx, x, x2);
  ln2_kernel<<<BT, 256, 0, stream>>>(x2, n2w, n2b, xn2);
  {
    dim3 g(4 * C_ / 64, (BT + 63) / 64);
    gemm_f32<<<g, 256, 0, stream>>>(xn2, fc1w, h32, fc1b, nullptr, BT, C_, 4 * C_);
  }
  gelu_kernel<<<(BT * 4 * C_) / 1024, 256, 0, stream>>>(h32);
  {
    dim3 g(C_ / 64, (BT + 63) / 64);
    gemm_f32<<<g, 256, 0, stream>>>(h32, fc2w, cbuf, fc2b, nullptr, BT, 4 * C_, C_);
  }
  e4_kernel<<<BT, 256, 0, stream>>>(x2, cbuf, poln, out_x);
}

// Round 10
// 2030.754 us; speedup vs baseline: 2.1377x; 1.9693x over previous
//
#include <hip/hip_runtime.h>
#include <hip/hip_bf16.h>
#include <float.h>
#include <math.h>
#include <stdint.h>

constexpr int B_   = 8;
constexpr int N_   = 785;
constexpr int C_   = 768;
constexpr int H_   = 12;
constexpr int DH_  = 64;
constexpr int NT_  = 393;
constexpr int QKVC = 3 * C_;   // 2304
constexpr int BN   = B_ * N_;  // 6280
constexpr int BT   = B_ * NT_; // 3144
constexpr int MSEL = N_ - 1;   // 784
constexpr float  SCALE_F = 0.125f;
constexpr double LNEPS   = 1e-5;
constexpr double SMEPS   = 1e-6;

#define DEV static __device__ __forceinline__

typedef __hip_bfloat16 bf16;

// ---------------- block reductions ----------------
DEV double blockReduceSumD(double v, double* scratch, int nw) {
#pragma unroll
  for (int o = 32; o; o >>= 1) v += __shfl_xor(v, o);
  int lane = threadIdx.x & 63, wid = threadIdx.x >> 6;
  __syncthreads();
  if (lane == 0) scratch[wid] = v;
  __syncthreads();
  double r = scratch[0];
  for (int i = 1; i < nw; i++) r += scratch[i];
  return r;
}
DEV double blockReduceMaxD(double v, double* scratch, int nw) {
#pragma unroll
  for (int o = 32; o; o >>= 1) v = fmax(v, __shfl_xor(v, o));
  int lane = threadIdx.x & 63, wid = threadIdx.x >> 6;
  __syncthreads();
  if (lane == 0) scratch[wid] = v;
  __syncthreads();
  double r = scratch[0];
  for (int i = 1; i < nw; i++) r = fmax(r, scratch[i]);
  return r;
}
DEV float blockReduceSumF(float v, float* scratch, int nw) {
#pragma unroll
  for (int o = 32; o; o >>= 1) v += __shfl_xor(v, o);
  int lane = threadIdx.x & 63, wid = threadIdx.x >> 6;
  __syncthreads();
  if (lane == 0) scratch[wid] = v;
  __syncthreads();
  float r = scratch[0];
  for (int i = 1; i < nw; i++) r += scratch[i];
  return r;
}
DEV float blockReduceMaxF(float v, float* scratch, int nw) {
#pragma unroll
  for (int o = 32; o; o >>= 1) v = fmaxf(v, __shfl_xor(v, o));
  int lane = threadIdx.x & 63, wid = threadIdx.x >> 6;
  __syncthreads();
  if (lane == 0) scratch[wid] = v;
  __syncthreads();
  float r = scratch[0];
  for (int i = 1; i < nw; i++) r = fmaxf(r, scratch[i]);
  return r;
}

// ---------------- LN1: x(f32) -> xn64 (fp64 scoring) + xn32 (fp32 value) ----------
__global__ __launch_bounds__(256) void ln1_kernel(
    const float* __restrict__ x, const float* __restrict__ w, const float* __restrict__ b,
    double* __restrict__ xn64, float* __restrict__ xn32) {
  int row = blockIdx.x;
  int t = threadIdx.x;
  __shared__ double scr[8];
  const float* xr = x + (size_t)row * C_;
  double vals[3];
#pragma unroll
  for (int i = 0; i < 3; i++) vals[i] = (double)xr[t + i * 256];
  double s = vals[0] + vals[1] + vals[2];
  s = blockReduceSumD(s, scr, 4);
  double mean = s / (double)C_;
  double vs = 0.0;
#pragma unroll
  for (int i = 0; i < 3; i++) { double d = vals[i] - mean; vs += d * d; }
  vs = blockReduceSumD(vs, scr, 4);
  double inv = 1.0 / sqrt(vs / (double)C_ + LNEPS);
#pragma unroll
  for (int i = 0; i < 3; i++) {
    int c = t + i * 256;
    double o = (vals[i] - mean) * inv * (double)w[c] + (double)b[c];
    xn64[(size_t)row * C_ + c] = o;
    xn32[(size_t)row * C_ + c] = (float)o;
  }
}

// ---------------- fp32 GEMM: C = A[MxK] @ W[KxN] (+bias)(*rowscale) ----------------
__global__ __launch_bounds__(256) void gemm_f32(
    const float* __restrict__ A, const float* __restrict__ W, float* __restrict__ Cc,
    const float* __restrict__ bias, const float* __restrict__ rowscale,
    int M, int K, int Ncols) {
  __shared__ float As[16][68];
  __shared__ float Bs[16][68];
  int t = threadIdx.x;
  int n0 = blockIdx.x * 64;
  int m0 = blockIdx.y * 64;
  int tm = (t >> 4) << 2, tn = (t & 15) << 2;
  float acc[4][4] = {{0.f}};
  int lm = t >> 2;
  int lk = (t & 3) << 2;
  bool mvalid = (m0 + lm) < M;
  for (int k0 = 0; k0 < K; k0 += 16) {
    float4 av = make_float4(0.f, 0.f, 0.f, 0.f);
    if (mvalid) av = *(const float4*)(A + (size_t)(m0 + lm) * K + k0 + lk);
    As[lk + 0][lm] = av.x; As[lk + 1][lm] = av.y;
    As[lk + 2][lm] = av.z; As[lk + 3][lm] = av.w;
#pragma unroll
    for (int i = 0; i < 4; i++) {
      int idx = t + i * 256;
      int n = idx & 63, k = idx >> 6;
      Bs[k][n] = W[(size_t)(k0 + k) * Ncols + n0 + n];
    }
    __syncthreads();
#pragma unroll
    for (int k = 0; k < 16; k++) {
      float a0 = As[k][tm + 0], a1 = As[k][tm + 1], a2 = As[k][tm + 2], a3 = As[k][tm + 3];
      float b0 = Bs[k][tn + 0], b1 = Bs[k][tn + 1], b2 = Bs[k][tn + 2], b3 = Bs[k][tn + 3];
      acc[0][0] += a0 * b0; acc[0][1] += a0 * b1; acc[0][2] += a0 * b2; acc[0][3] += a0 * b3;
      acc[1][0] += a1 * b0; acc[1][1] += a1 * b1; acc[1][2] += a1 * b2; acc[1][3] += a1 * b3;
      acc[2][0] += a2 * b0; acc[2][1] += a2 * b1; acc[2][2] += a2 * b2; acc[2][3] += a2 * b3;
      acc[3][0] += a3 * b0; acc[3][1] += a3 * b1; acc[3][2] += a3 * b2; acc[3][3] += a3 * b3;
    }
    __syncthreads();
  }
#pragma unroll
  for (int i = 0; i < 4; i++) {
    int m = m0 + tm + i;
    if (m >= M) continue;
    float rs = rowscale ? rowscale[m] : 1.0f;
#pragma unroll
    for (int j = 0; j < 4; j++) {
      int n = n0 + tn + j;
      float v = acc[i][j];
      if (bias) v += bias[n];
      Cc[(size_t)m * Ncols + n] = v * rs;
    }
  }
}

// ---------------- q0 (row-0 query, fp64) ----------------
__global__ __launch_bounds__(256) void q0_kernel(
    const double* __restrict__ xn64, const float* __restrict__ qkvw,
    const float* __restrict__ policy, double* __restrict__ q064) {
  int b = blockIdx.x;
  int t = threadIdx.x;
  __shared__ double x0[C_];
  for (int i = t; i < C_; i += 256) x0[i] = xn64[(size_t)(b * N_) * C_ + i];
  __syncthreads();
  double pol = (double)policy[b * N_];
  for (int j = t; j < C_; j += 256) {
    double a = 0.0;
    for (int c = 0; c < C_; c++) a += x0[c] * (double)qkvw[(size_t)c * QKVC + j];
    q064[b * C_ + j] = a * pol;
  }
}

// ---------------- g[b,h,c] (fp64) ----------------
__global__ __launch_bounds__(256) void g_kernel(
    const double* __restrict__ q064, const float* __restrict__ qkvw,
    double* __restrict__ g64) {
  int bh = blockIdx.x;
  int b = bh / H_, h = bh % H_;
  int t = threadIdx.x;
  __shared__ double qh[DH_];
  if (t < DH_) qh[t] = q064[b * C_ + h * DH_ + t];
  __syncthreads();
  for (int c = t; c < C_; c += 256) {
    const float* wp = qkvw + (size_t)c * QKVC + C_ + h * DH_;
    double a = 0.0;
#pragma unroll 8
    for (int d = 0; d < DH_; d++) a += qh[d] * (double)wp[d];
    g64[(size_t)bh * C_ + c] = a;
  }
}

// ---------------- row-0 logits fp64 ----------------
__global__ __launch_bounds__(256) void logits_kernel(
    const double* __restrict__ xn64, const double* __restrict__ g64,
    const float* __restrict__ policy, double* __restrict__ l64) {
  int row = blockIdx.x;
  int b = row / N_;
  int n = row % N_;
  int t = threadIdx.x;
  __shared__ double xr[C_];
  __shared__ double scr[8];
  for (int i = t; i < C_; i += 256) xr[i] = xn64[(size_t)row * C_ + i];
  __syncthreads();
  double pol = (double)policy[row];
  for (int h = 0; h < H_; h++) {
    const double* gp = g64 + (size_t)(b * H_ + h) * C_;
    double p = 0.0;
    for (int i = t; i < C_; i += 256) p += xr[i] * gp[i];
    double s = blockReduceSumD(p, scr, 4);
    if (t == 0) l64[(size_t)(b * H_ + h) * N_ + n] = 0.125 * pol * s;
  }
}

// ---------------- ||v||^2 fp64 (staged row-block; pol^2 baked in) -----------------
__global__ __launch_bounds__(256) void vnorm_kernel(
    const double* __restrict__ xn64, const float* __restrict__ qkvw,
    const float* __restrict__ policy, double* __restrict__ vnorm2) {
  __shared__ double xr[8][C_];
  __shared__ double scr[8];
  int r0 = blockIdx.x * 8;
  int t = threadIdx.x;
  for (int i = t; i < 8 * C_; i += 256)
    xr[i / C_][i % C_] = xn64[(size_t)(r0 + i / C_) * C_ + (i % C_)];
  __syncthreads();
  double acc[8][3] = {};
  for (int c = 0; c < C_; c++) {
    const float* wp = qkvw + (size_t)c * QKVC + 2 * C_;
    double w0 = (double)wp[t];
    double w1 = (double)wp[t + 256];
    double w2 = (double)wp[t + 512];
#pragma unroll
    for (int r = 0; r < 8; r++) {
      double xv = xr[r][c];
      acc[r][0] += xv * w0; acc[r][1] += xv * w1; acc[r][2] += xv * w2;
    }
  }
  for (int r = 0; r < 8; r++) {
    double p = acc[r][0] * acc[r][0] + acc[r][1] * acc[r][1] + acc[r][2] * acc[r][2];
    double s = blockReduceSumD(p, scr, 4);
    if (t == 0) {
      double pol = (double)policy[r0 + r];
      vnorm2[r0 + r] = s * pol * pol;
    }
  }
}

// ---------------- row-0 softmax fp64 (in place) ----------------
__global__ __launch_bounds__(256) void softmax0_kernel(
    double* __restrict__ l64, const float* __restrict__ policy) {
  int bh = blockIdx.x;
  int b = bh / H_;
  double* lp = l64 + (size_t)bh * N_;
  __shared__ double scr[8];
  int t = threadIdx.x;
  double mx = -1e300;
  for (int n = t; n < N_; n += 256) mx = fmax(mx, lp[n]);
  mx = blockReduceMaxD(mx, scr, 4);
  double ssum = 0.0;
  for (int n = t; n < N_; n += 256) {
    double pol = (double)policy[b * N_ + n];
    double w = (n == 0) ? 1.0 : pol;
    double e = exp(lp[n] - mx) * w;
    lp[n] = e;
    ssum += e;
  }
  ssum = blockReduceSumD(ssum, scr, 4);
  double denom = ssum + SMEPS;
  double addc = SMEPS / (double)N_;
  for (int n = t; n < N_; n += 256) lp[n] = (lp[n] + addc) / denom;
}

// ---------------- selection fp64, paranoid-simple ----------------
__global__ __launch_bounds__(1024) void select_kernel(
    const double* __restrict__ p0, const double* __restrict__ vnorm2,
    int* __restrict__ selidx, float* __restrict__ poln, float* __restrict__ out_pol) {
  int b = blockIdx.x;
  int t = threadIdx.x;
  __shared__ double sigv[MSEL];
  __shared__ double svals[MSEL];
  __shared__ double nc[MSEL];
  __shared__ int    ord[MSEL];
  __shared__ int    pick[MSEL];
  __shared__ int    spick[MSEL];
  __shared__ int    uq[MSEL];
  __shared__ int    suq[MSEL];
  __shared__ double sh_ys;

  if (t < MSEL) {
    int n = t + 1;
    double s = 0.0;
#pragma unroll
    for (int h = 0; h < H_; h++) s += p0[(size_t)(b * H_ + h) * N_ + n];
    sigv[t] = s * sqrt(vnorm2[b * N_ + n]);
  }
  __syncthreads();
  if (t < MSEL) {
    double v = sigv[t];
    int rank = 0;
    for (int i = 0; i < MSEL; i++) {
      double vi = sigv[i];
      rank += (vi < v) || (vi == v && i < t);
    }
    ord[rank] = t;
    svals[rank] = v;
  }
  __syncthreads();
  if (t == 0) {
    double a = 0.0;
    for (int i = 0; i < MSEL; i++) { a += svals[i]; svals[i] = a; }
  }
  __syncthreads();
  {
    double c0 = svals[0], cN = svals[MSEL - 1];
    if (t < MSEL) nc[t] = (svals[t] - c0) / (cN - c0);
  }
  __syncthreads();
  if (t == 0) {
    double m = 1e300;
    for (int i = 0; i < MSEL; i++) {
      double v = nc[i];
      if (v == 0.0) v += 100000000.0;
      m = fmin(m, v);
    }
    sh_ys = m;
  }
  __syncthreads();
  if (t < MSEL) {
    double s = sh_ys;
    double ysj = (t == MSEL - 1) ? 1.0 : (double)t / 783.0;
    double y = s + (ysj * 783.0 - s * (double)t) / 783.0;
    double bd = 1e300;
    int bi = 0;
    for (int i = 0; i < MSEL; i++) {
      double d = fabs(y - nc[i]);
      if (d < bd) { bd = d; bi = i; }
    }
    pick[t] = bi;
  }
  __syncthreads();
  if (t < MSEL) {
    int p = pick[t];
    int rank = 0;
    for (int i = 0; i < MSEL; i++) {
      int pi = pick[i];
      rank += (pi < p) || (pi == p && i < t);
    }
    spick[rank] = p;
  }
  __syncthreads();
  if (t < MSEL) {
    int s = spick[t];
    int nxt = (t < MSEL - 1) ? spick[t + 1] : 1;
    uq[t] = (nxt == s) ? MSEL : s;
  }
  __syncthreads();
  if (t < MSEL) {
    int u = uq[t];
    int rank = 0;
    for (int i = 0; i < MSEL; i++) {
      int ui = uq[i];
      rank += (ui < u) || (ui == u && i < t);
    }
    suq[rank] = u;
  }
  __syncthreads();
  if (t < NT_) {
    int sel, polI;
    if (t == 0) { sel = 0; polI = 1; }
    else {
      int ut = suq[t - 1];
      polI = (ut != MSEL) ? 1 : 0;
      sel = polI ? (ord[ut] + 1) : -1;
    }
    selidx[b * NT_ + t] = sel;
    poln[b * NT_ + t] = (float)polI;
    out_pol[b * NT_ + t] = (float)polI;
  }
}

// ---------------- Phase A: S = scale * Q_sel @ K^T  per (b,h) ----------------
__global__ __launch_bounds__(256) void qk_kernel(
    const float* __restrict__ qkv, const int* __restrict__ selidx,
    float* __restrict__ S) {
  int bh = blockIdx.z;
  int b = bh / H_, h = bh % H_;
  int j0 = blockIdx.y * 64;
  int n0 = blockIdx.x * 64;
  int t = threadIdx.x;
  __shared__ float Qs[64][68];   // [k][m]
  __shared__ float Ks[64][68];   // [k][n]
  int lm = t >> 2;           // 0..63
  int kb = (t & 3) * 16;     // 0,16,32,48
  {
    int j = j0 + lm;
    int r = (j < NT_) ? selidx[b * NT_ + j] : -1;
    if (r < 0) r = 0;  // finite garbage; masked by pol_new downstream
    const float* qp = qkv + (size_t)(b * N_ + r) * QKVC + h * DH_ + kb;
    float4 v0 = *(const float4*)(qp + 0);
    float4 v1 = *(const float4*)(qp + 4);
    float4 v2 = *(const float4*)(qp + 8);
    float4 v3 = *(const float4*)(qp + 12);
    Qs[kb + 0][lm] = v0.x; Qs[kb + 1][lm] = v0.y; Qs[kb + 2][lm] = v0.z; Qs[kb + 3][lm] = v0.w;
    Qs[kb + 4][lm] = v1.x; Qs[kb + 5][lm] = v1.y; Qs[kb + 6][lm] = v1.z; Qs[kb + 7][lm] = v1.w;
    Qs[kb + 8][lm] = v2.x; Qs[kb + 9][lm] = v2.y; Qs[kb +10][lm] = v2.z; Qs[kb +11][lm] = v2.w;
    Qs[kb +12][lm] = v3.x; Qs[kb +13][lm] = v3.y; Qs[kb +14][lm] = v3.z; Qs[kb +15][lm] = v3.w;
  }
  {
    int n = n0 + lm;
    bool ok = n < N_;
    const float* kp = qkv + (size_t)(b * N_ + (ok ? n : 0)) * QKVC + C_ + h * DH_ + kb;
    float4 v0 = ok ? *(const float4*)(kp + 0)  : make_float4(0, 0, 0, 0);
    float4 v1 = ok ? *(const float4*)(kp + 4)  : make_float4(0, 0, 0, 0);
    float4 v2 = ok ? *(const float4*)(kp + 8)  : make_float4(0, 0, 0, 0);
    float4 v3 = ok ? *(const float4*)(kp + 12) : make_float4(0, 0, 0, 0);
    Ks[kb + 0][lm] = v0.x; Ks[kb + 1][lm] = v0.y; Ks[kb + 2][lm] = v0.z; Ks[kb + 3][lm] = v0.w;
    Ks[kb + 4][lm] = v1.x; Ks[kb + 5][lm] = v1.y; Ks[kb + 6][lm] = v1.z; Ks[kb + 7][lm] = v1.w;
    Ks[kb + 8][lm] = v2.x; Ks[kb + 9][lm] = v2.y; Ks[kb +10][lm] = v2.z; Ks[kb +11][lm] = v2.w;
    Ks[kb +12][lm] = v3.x; Ks[kb +13][lm] = v3.y; Ks[kb +14][lm] = v3.z; Ks[kb +15][lm] = v3.w;
  }
  __syncthreads();
  int tm = (t >> 4) << 2, tn = (t & 15) << 2;
  float acc[4][4] = {{0.f}};
#pragma unroll 16
  for (int k = 0; k < 64; k++) {
    float a0 = Qs[k][tm + 0], a1 = Qs[k][tm + 1], a2 = Qs[k][tm + 2], a3 = Qs[k][tm + 3];
    float b0 = Ks[k][tn + 0], b1 = Ks[k][tn + 1], b2 = Ks[k][tn + 2], b3 = Ks[k][tn + 3];
    acc[0][0] += a0 * b0; acc[0][1] += a0 * b1; acc[0][2] += a0 * b2; acc[0][3] += a0 * b3;
    acc[1][0] += a1 * b0; acc[1][1] += a1 * b1; acc[1][2] += a1 * b2; acc[1][3] += a1 * b3;
    acc[2][0] += a2 * b0; acc[2][1] += a2 * b1; acc[2][2] += a2 * b2; acc[2][3] += a2 * b3;
    acc[3][0] += a3 * b0; acc[3][1] += a3 * b1; acc[3][2] += a3 * b2; acc[3][3] += a3 * b3;
  }
#pragma unroll
  for (int i = 0; i < 4; i++) {
    int j = j0 + tm + i;
    if (j >= NT_) continue;
#pragma unroll
    for (int jj = 0; jj < 4; jj++) {
      int n = n0 + tn + jj;
      if (n >= N_) continue;
      S[((size_t)bh * NT_ + j) * N_ + n] = acc[i][jj] * SCALE_F;
    }
  }
}

// ---------------- Phase B: softmax-with-policy over S rows ----------------
__global__ __launch_bounds__(256) void smax_kernel(
    float* __restrict__ S, const int* __restrict__ selidx,
    const float* __restrict__ policy) {
  int row = blockIdx.x;  // b*NT + j
  int b = row / NT_;
  int j = row - b * NT_;
  int r = selidx[row];
  int t = threadIdx.x;
  __shared__ float buf[N_];
  __shared__ float fscr[8];
  for (int h = 0; h < H_; h++) {
    float* sp = S + ((size_t)(b * H_ + h) * NT_ + j) * N_;
    float m = -1e30f;
    for (int n = t; n < N_; n += 256) { float v = sp[n]; buf[n] = v; m = fmaxf(m, v); }
    m = blockReduceMaxF(m, fscr, 4);
    float p = 0.f;
    for (int n = t; n < N_; n += 256) {
      float pol = policy[b * N_ + n];
      float w = (n == r) ? 1.0f : pol;
      float e = expf(buf[n] - m) * w;
      buf[n] = e;
      p += e;
    }
    float Ssum = blockReduceSumF(p, fscr, 4);
    float denom = Ssum + 1e-6f;
    float addc = 1e-6f / (float)N_;
    for (int n = t; n < N_; n += 256) sp[n] = (buf[n] + addc) / denom;
    __syncthreads();
  }
}

// ---------------- Phase C: attn_o = P @ V  per (b,h) ----------------
__global__ __launch_bounds__(256) void pv_kernel(
    const float* __restrict__ S, const float* __restrict__ qkv,
    float* __restrict__ attn_o) {
  int bh = blockIdx.z;
  int b = bh / H_, h = bh % H_;
  int j0 = blockIdx.y * 64;
  int t = threadIdx.x;
  __shared__ float Ps[16][68];
  __shared__ float Vs[16][68];
  int tm = (t >> 4) << 2, tn = (t & 15) << 2;
  float acc[4][4] = {{0.f}};
  int lm = t >> 2;          // P row (m)
  int lk = (t & 3) << 2;    // P k offset
  int vd = t & 63;          // V d
  int vk4 = (t >> 6) * 4;   // V k group
  for (int k0 = 0; k0 < N_; k0 += 16) {
#pragma unroll
    for (int i = 0; i < 4; i++) {
      int kk = k0 + lk + i;
      float v = 0.f;
      if (j0 + lm < NT_ && kk < N_)
        v = S[((size_t)bh * NT_ + j0 + lm) * N_ + kk];
      Ps[lk + i][lm] = v;
    }
#pragma unroll
    for (int i = 0; i < 4; i++) {
      int kk = k0 + vk4 + i;
      float v = 0.f;
      if (kk < N_)
        v = qkv[(size_t)(b * N_ + kk) * QKVC + 2 * C_ + h * DH_ + vd];
      Vs[vk4 + i][vd] = v;
    }
    __syncthreads();
#pragma unroll
    for (int k = 0; k < 16; k++) {
      float a0 = Ps[k][tm + 0], a1 = Ps[k][tm + 1], a2 = Ps[k][tm + 2], a3 = Ps[k][tm + 3];
      float b0 = Vs[k][tn + 0], b1 = Vs[k][tn + 1], b2 = Vs[k][tn + 2], b3 = Vs[k][tn + 3];
      acc[0][0] += a0 * b0; acc[0][1] += a0 * b1; acc[0][2] += a0 * b2; acc[0][3] += a0 * b3;
      acc[1][0] += a1 * b0; acc[1][1] += a1 * b1; acc[1][2] += a1 * b2; acc[1][3] += a1 * b3;
      acc[2][0] += a2 * b0; acc[2][1] += a2 * b1; acc[2][2] += a2 * b2; acc[2][3] += a2 * b3;
      acc[3][0] += a3 * b0; acc[3][1] += a3 * b1; acc[3][2] += a3 * b2; acc[3][3] += a3 * b3;
    }
    __syncthreads();
  }
#pragma unroll
  for (int i = 0; i < 4; i++) {
    int m = j0 + tm + i;
    if (m >= NT_) continue;
#pragma unroll
    for (int jj = 0; jj < 4; jj++) {
      attn_o[(size_t)(b * NT_ + m) * C_ + h * DH_ + tn + jj] = acc[i][jj];
    }
  }
}

// ---------------- epilogues ----------------
__global__ __launch_bounds__(256) void e2_kernel(
    const float* __restrict__ cbuf, const float* __restrict__ poln,
    const int* __restrict__ selidx, const float* __restrict__ x, float* __restrict__ x2) {
  int row = blockIdx.x;
  int t = threadIdx.x;
  int b = row / NT_;
  int r = selidx[row];
  float pn = poln[row];
  for (int i = t; i < C_; i += 256) {
    float sx = (r >= 0) ? x[(size_t)(b * N_ + r) * C_ + i] : 0.f;
    x2[(size_t)row * C_ + i] = sx + cbuf[(size_t)row * C_ + i] * pn;
  }
}

__global__ __launch_bounds__(256) void ln2_kernel(
    const float* __restrict__ xin, const float* __restrict__ w, const float* __restrict__ b,
    float* __restrict__ xout) {
  int row = blockIdx.x;
  int t = threadIdx.x;
  __shared__ float scr[8];
  const float* xr = xin + (size_t)row * C_;
  float vals[3];
#pragma unroll
  for (int i = 0; i < 3; i++) vals[i] = xr[t + i * 256];
  float s = vals[0] + vals[1] + vals[2];
  s = blockReduceSumF(s, scr, 4);
  float mean = s / (float)C_;
  float vs = 0.f;
#pragma unroll
  for (int i = 0; i < 3; i++) { float d = vals[i] - mean; vs += d * d; }
  vs = blockReduceSumF(vs, scr, 4);
  float sd = sqrtf(vs / (float)C_ + 1e-5f);
#pragma unroll
  for (int i = 0; i < 3; i++) {
    int c = t + i * 256;
    xout[(size_t)row * C_ + c] = (vals[i] - mean) / sd * w[c] + b[c];
  }
}

DEV float gelu_exact(float v) { return 0.5f * v * (1.0f + erff(v * 0.70710678118654752f)); }

__global__ __launch_bounds__(256) void gelu_kernel(float* __restrict__ h) {
  size_t i = (size_t)blockIdx.x * 256 + threadIdx.x;
  float4 v = ((float4*)h)[i];
  v.x = gelu_exact(v.x); v.y = gelu_exact(v.y);
  v.z = gelu_exact(v.z); v.w = gelu_exact(v.w);
  ((float4*)h)[i] = v;
}

__global__ __launch_bounds__(256) void e4_kernel(
    const float* __restrict__ x2, const float* __restrict__ cbuf,
    const float* __restrict__ poln, float* __restrict__ out) {
  int row = blockIdx.x;
  int t = threadIdx.x;
  float pn = poln[row];
  for (int i = t; i < C_; i += 256) {
    float v = x2[(size_t)row * C_ + i] + cbuf[(size_t)row * C_ + i] * pn;
    out[(size_t)row * C_ + i] = v;
  }
}

// ---------------- launcher ----------------
extern "C" void kernel_launch(void* const* d_in, const int* in_sizes, int n_in,
                              void* d_out, int out_size, void* d_ws, size_t ws_size,
                              hipStream_t stream) {
  const float* x      = (const float*)d_in[0];
  const float* policy = (const float*)d_in[1];
  const float* n1w    = (const float*)d_in[2];
  const float* n1b    = (const float*)d_in[3];
  const float* qkvw   = (const float*)d_in[4];
  const float* projw  = (const float*)d_in[5];
  const float* projb  = (const float*)d_in[6];
  const float* n2w    = (const float*)d_in[7];
  const float* n2b    = (const float*)d_in[8];
  const float* fc1w   = (const float*)d_in[9];
  const float* fc1b   = (const float*)d_in[10];
  const float* fc2w   = (const float*)d_in[11];
  const float* fc2b   = (const float*)d_in[12];

  char* ws = (char*)d_ws;
  size_t off = 0;
  auto alloc = [&](size_t bytes) {
    size_t o = off;
    off += (bytes + 255) & ~(size_t)255;
    return o;
  };

  double* xn64   = (double*)(ws + alloc((size_t)BN * C_ * 8));
  float*  xn32   = (float*)(ws + alloc((size_t)BN * C_ * 4));
  float*  qkv32  = (float*)(ws + alloc((size_t)BN * QKVC * 4));
  double* vnorm2 = (double*)(ws + alloc((size_t)BN * 8));
  double* q064   = (double*)(ws + alloc((size_t)B_ * C_ * 8));
  double* g64    = (double*)(ws + alloc((size_t)B_ * H_ * C_ * 8));
  double* l64    = (double*)(ws + alloc((size_t)B_ * H_ * N_ * 8));
  int*    selidx = (int*)(ws + alloc((size_t)BT * 4));
  float*  poln   = (float*)(ws + alloc((size_t)BT * 4));
  float*  attn_o = (float*)(ws + alloc((size_t)BT * C_ * 4));
  float*  cbuf   = (float*)(ws + alloc((size_t)BT * C_ * 4));
  float*  x2     = (float*)(ws + alloc((size_t)BT * C_ * 4));

  // UNION: S (scores, dead after pv_kernel) overlaps xn2 + h32 (used after).
  size_t S_bytes   = (size_t)B_ * H_ * NT_ * N_ * 4;   // ~118 MB
  size_t xn2_bytes = ((size_t)BT * C_ * 4 + 255) & ~(size_t)255;
  size_t late_bytes = xn2_bytes + (size_t)BT * 4 * C_ * 4;
  size_t union_bytes = S_bytes > late_bytes ? S_bytes : late_bytes;
  char* ub   = ws + alloc(union_bytes);
  float* Sbuf = (float*)ub;
  float* xn2  = (float*)ub;
  float* h32  = (float*)(ub + xn2_bytes);
  if (off > ws_size) return;

  float* out_x = (float*)d_out;
  float* out_p = out_x + (size_t)BT * C_;

  ln1_kernel<<<BN, 256, 0, stream>>>(x, n1w, n1b, xn64, xn32);

  {
    dim3 g(QKVC / 64, (BN + 63) / 64);
    gemm_f32<<<g, 256, 0, stream>>>(xn32, qkvw, qkv32, nullptr, policy, BN, C_, QKVC);
  }

  // fp64 scoring path
  q0_kernel<<<B_, 256, 0, stream>>>(xn64, qkvw, policy, q064);
  g_kernel<<<B_ * H_, 256, 0, stream>>>(q064, qkvw, g64);
  logits_kernel<<<BN, 256, 0, stream>>>(xn64, g64, policy, l64);
  vnorm_kernel<<<BN / 8, 256, 0, stream>>>(xn64, qkvw, policy, vnorm2);
  softmax0_kernel<<<B_ * H_, 256, 0, stream>>>(l64, policy);
  select_kernel<<<B_, 1024, 0, stream>>>(l64, vnorm2, selidx, poln, out_p);

  // attention as 3 GEMM-shaped phases
  {
    dim3 g((N_ + 63) / 64, (NT_ + 63) / 64, B_ * H_);   // (13, 7, 96)
    qk_kernel<<<g, 256, 0, stream>>>(qkv32, selidx, Sbuf);
  }
  smax_kernel<<<BT, 256, 0, stream>>>(Sbuf, selidx, policy);
  {
    dim3 g(1, (NT_ + 63) / 64, B_ * H_);                 // (1, 7, 96)
    pv_kernel<<<g, 256, 0, stream>>>(Sbuf, qkv32, attn_o);
  }

  {
    dim3 g(C_ / 64, (BT + 63) / 64);
    gemm_f32<<<g, 256, 0, stream>>>(attn_o, projw, cbuf, projb, nullptr, BT, C_, C_);
  }
  e2_kernel<<<BT, 256, 0, stream>>>(cbuf, poln, selidx, x, x2);
  ln2_kernel<<<BT, 256, 0, stream>>>(x2, n2w, n2b, xn2);
  {
    dim3 g(4 * C_ / 64, (BT + 63) / 64);
    gemm_f32<<<g, 256, 0, stream>>>(xn2, fc1w, h32, fc1b, nullptr, BT, C_, 4 * C_);
  }
  gelu_kernel<<<(BT * 4 * C_) / 1024, 256, 0, stream>>>(h32);
  {
    dim3 g(C_ / 64, (BT + 63) / 64);
    gemm_f32<<<g, 256, 0, stream>>>(h32, fc2w, cbuf, fc2b, nullptr, BT, 4 * C_, C_);
  }
  e4_kernel<<<BT, 256, 0, stream>>>(x2, cbuf, poln, out_x);
}

// Round 11
// 1259.167 us; speedup vs baseline: 3.4477x; 1.6128x over previous
//
#include <hip/hip_runtime.h>
#include <hip/hip_bf16.h>
#include <float.h>
#include <math.h>
#include <stdint.h>

constexpr int B_   = 8;
constexpr int N_   = 785;
constexpr int C_   = 768;
constexpr int H_   = 12;
constexpr int DH_  = 64;
constexpr int NT_  = 393;
constexpr int QKVC = 3 * C_;   // 2304
constexpr int BN   = B_ * N_;  // 6280
constexpr int BT   = B_ * NT_; // 3144
constexpr int MSEL = N_ - 1;   // 784
constexpr float  SCALE_F = 0.125f;
constexpr double LNEPS   = 1e-5;
constexpr double SMEPS   = 1e-6;

#define DEV static __device__ __forceinline__

typedef __hip_bfloat16 bf16;
typedef __attribute__((ext_vector_type(8))) short frag8;
typedef __attribute__((ext_vector_type(4))) float facc4;

// ---------------- block reductions ----------------
DEV double blockReduceSumD(double v, double* scratch, int nw) {
#pragma unroll
  for (int o = 32; o; o >>= 1) v += __shfl_xor(v, o);
  int lane = threadIdx.x & 63, wid = threadIdx.x >> 6;
  __syncthreads();
  if (lane == 0) scratch[wid] = v;
  __syncthreads();
  double r = scratch[0];
  for (int i = 1; i < nw; i++) r += scratch[i];
  return r;
}
DEV double blockReduceMaxD(double v, double* scratch, int nw) {
#pragma unroll
  for (int o = 32; o; o >>= 1) v = fmax(v, __shfl_xor(v, o));
  int lane = threadIdx.x & 63, wid = threadIdx.x >> 6;
  __syncthreads();
  if (lane == 0) scratch[wid] = v;
  __syncthreads();
  double r = scratch[0];
  for (int i = 1; i < nw; i++) r = fmax(r, scratch[i]);
  return r;
}
DEV float blockReduceSumF(float v, float* scratch, int nw) {
#pragma unroll
  for (int o = 32; o; o >>= 1) v += __shfl_xor(v, o);
  int lane = threadIdx.x & 63, wid = threadIdx.x >> 6;
  __syncthreads();
  if (lane == 0) scratch[wid] = v;
  __syncthreads();
  float r = scratch[0];
  for (int i = 1; i < nw; i++) r += scratch[i];
  return r;
}
DEV float blockReduceMaxF(float v, float* scratch, int nw) {
#pragma unroll
  for (int o = 32; o; o >>= 1) v = fmaxf(v, __shfl_xor(v, o));
  int lane = threadIdx.x & 63, wid = threadIdx.x >> 6;
  __syncthreads();
  if (lane == 0) scratch[wid] = v;
  __syncthreads();
  float r = scratch[0];
  for (int i = 1; i < nw; i++) r = fmaxf(r, scratch[i]);
  return r;
}

// ---------------- LN1: x(f32) -> xn64 (fp64 scoring) + xn_bf (bf16 value) --------
__global__ __launch_bounds__(256) void ln1_kernel(
    const float* __restrict__ x, const float* __restrict__ w, const float* __restrict__ b,
    double* __restrict__ xn64, bf16* __restrict__ xnb) {
  int row = blockIdx.x;
  int t = threadIdx.x;
  __shared__ double scr[8];
  const float* xr = x + (size_t)row * C_;
  double vals[3];
#pragma unroll
  for (int i = 0; i < 3; i++) vals[i] = (double)xr[t + i * 256];
  double s = vals[0] + vals[1] + vals[2];
  s = blockReduceSumD(s, scr, 4);
  double mean = s / (double)C_;
  double vs = 0.0;
#pragma unroll
  for (int i = 0; i < 3; i++) { double d = vals[i] - mean; vs += d * d; }
  vs = blockReduceSumD(vs, scr, 4);
  double inv = 1.0 / sqrt(vs / (double)C_ + LNEPS);
#pragma unroll
  for (int i = 0; i < 3; i++) {
    int c = t + i * 256;
    double o = (vals[i] - mean) * inv * (double)w[c] + (double)b[c];
    xn64[(size_t)row * C_ + c] = o;
    xnb[(size_t)row * C_ + c] = __float2bfloat16((float)o);
  }
}

// ---------------- weight transpose+convert: W[K][N] f32 -> Wt[N][K] bf16 ---------
__global__ __launch_bounds__(256) void transpose_bf16(
    const float* __restrict__ W, bf16* __restrict__ Wt, int K, int N) {
  __shared__ float tile[32][33];
  int k0 = blockIdx.y * 32, n0 = blockIdx.x * 32;
  int tx = threadIdx.x & 31, ty = threadIdx.x >> 5;  // ty 0..7
  for (int i = ty; i < 32; i += 8) {
    int k = k0 + i, n = n0 + tx;
    tile[i][tx] = (k < K && n < N) ? W[(size_t)k * N + n] : 0.f;
  }
  __syncthreads();
  for (int i = ty; i < 32; i += 8) {
    int n = n0 + i, k = k0 + tx;
    if (n < N && k < K) Wt[(size_t)n * K + k] = __float2bfloat16(tile[tx][i]);
  }
}

// ---------------- bf16 MFMA GEMM: C[MxN]f32 = A[MxK]bf16 @ Wt[NxK]bf16 -----------
// 64x64 tile / block of 256 threads (4 waves); wave w computes 16-row strip.
__global__ __launch_bounds__(256) void gemm_bf16(
    const bf16* __restrict__ A, const bf16* __restrict__ Bt,
    float* __restrict__ Cc, const float* __restrict__ bias,
    const float* __restrict__ rowscale, int M, int K, int Ncols) {
  __shared__ short As[64][40];
  __shared__ short Bs[64][40];
  const short* Ap = (const short*)A;
  const short* Bp = (const short*)Bt;
  int t = threadIdx.x;
  int n0 = blockIdx.x * 64;
  int m0 = blockIdx.y * 64;
  int w = t >> 6, l = t & 63;
  int srow = t >> 2;            // staging row 0..63
  int koff = (t & 3) * 8;       // staging k offset
  facc4 acc[4] = {{0, 0, 0, 0}, {0, 0, 0, 0}, {0, 0, 0, 0}, {0, 0, 0, 0}};
  int frow = (l & 15);          // fragment row-in-16
  int fk = (l >> 4) * 8;        // fragment k offset
  for (int k0 = 0; k0 < K; k0 += 32) {
    {
      int4 av = make_int4(0, 0, 0, 0);
      if (m0 + srow < M)
        av = *(const int4*)(Ap + (size_t)(m0 + srow) * K + k0 + koff);
      *(int4*)(&As[srow][koff]) = av;
      int4 bv = *(const int4*)(Bp + (size_t)(n0 + srow) * K + k0 + koff);
      *(int4*)(&Bs[srow][koff]) = bv;
    }
    __syncthreads();
    frag8 a = *(frag8*)(&As[w * 16 + frow][fk]);
#pragma unroll
    for (int nt = 0; nt < 4; nt++) {
      frag8 bfr = *(frag8*)(&Bs[nt * 16 + frow][fk]);
      acc[nt] = __builtin_amdgcn_mfma_f32_16x16x32_bf16(a, bfr, acc[nt], 0, 0, 0);
    }
    __syncthreads();
  }
#pragma unroll
  for (int nt = 0; nt < 4; nt++) {
#pragma unroll
    for (int reg = 0; reg < 4; reg++) {
      int row = m0 + w * 16 + (l >> 4) * 4 + reg;
      int col = n0 + nt * 16 + (l & 15);
      if (row < M) {
        float v = acc[nt][reg];
        if (bias) v += bias[col];
        if (rowscale) v *= rowscale[row];
        Cc[(size_t)row * Ncols + col] = v;
      }
    }
  }
}

// ---------------- q0 (row-0 query, fp64) ----------------
__global__ __launch_bounds__(256) void q0_kernel(
    const double* __restrict__ xn64, const float* __restrict__ qkvw,
    const float* __restrict__ policy, double* __restrict__ q064) {
  int b = blockIdx.x;
  int t = threadIdx.x;
  __shared__ double x0[C_];
  for (int i = t; i < C_; i += 256) x0[i] = xn64[(size_t)(b * N_) * C_ + i];
  __syncthreads();
  double pol = (double)policy[b * N_];
  for (int j = t; j < C_; j += 256) {
    double a = 0.0;
    for (int c = 0; c < C_; c++) a += x0[c] * (double)qkvw[(size_t)c * QKVC + j];
    q064[b * C_ + j] = a * pol;
  }
}

// ---------------- g[b,h,c] (fp64) ----------------
__global__ __launch_bounds__(256) void g_kernel(
    const double* __restrict__ q064, const float* __restrict__ qkvw,
    double* __restrict__ g64) {
  int bh = blockIdx.x;
  int b = bh / H_, h = bh % H_;
  int t = threadIdx.x;
  __shared__ double qh[DH_];
  if (t < DH_) qh[t] = q064[b * C_ + h * DH_ + t];
  __syncthreads();
  for (int c = t; c < C_; c += 256) {
    const float* wp = qkvw + (size_t)c * QKVC + C_ + h * DH_;
    double a = 0.0;
#pragma unroll 8
    for (int d = 0; d < DH_; d++) a += qh[d] * (double)wp[d];
    g64[(size_t)bh * C_ + c] = a;
  }
}

// ---------------- row-0 logits fp64 ----------------
__global__ __launch_bounds__(256) void logits_kernel(
    const double* __restrict__ xn64, const double* __restrict__ g64,
    const float* __restrict__ policy, double* __restrict__ l64) {
  int row = blockIdx.x;
  int b = row / N_;
  int n = row % N_;
  int t = threadIdx.x;
  __shared__ double xr[C_];
  __shared__ double scr[8];
  for (int i = t; i < C_; i += 256) xr[i] = xn64[(size_t)row * C_ + i];
  __syncthreads();
  double pol = (double)policy[row];
  for (int h = 0; h < H_; h++) {
    const double* gp = g64 + (size_t)(b * H_ + h) * C_;
    double p = 0.0;
    for (int i = t; i < C_; i += 256) p += xr[i] * gp[i];
    double s = blockReduceSumD(p, scr, 4);
    if (t == 0) l64[(size_t)(b * H_ + h) * N_ + n] = 0.125 * pol * s;
  }
}

// ---------------- ||v||^2 fp64 (staged row-block; pol^2 baked in) -----------------
__global__ __launch_bounds__(256) void vnorm_kernel(
    const double* __restrict__ xn64, const float* __restrict__ qkvw,
    const float* __restrict__ policy, double* __restrict__ vnorm2) {
  __shared__ double xr[8][C_];
  __shared__ double scr[8];
  int r0 = blockIdx.x * 8;
  int t = threadIdx.x;
  for (int i = t; i < 8 * C_; i += 256)
    xr[i / C_][i % C_] = xn64[(size_t)(r0 + i / C_) * C_ + (i % C_)];
  __syncthreads();
  double acc[8][3] = {};
  for (int c = 0; c < C_; c++) {
    const float* wp = qkvw + (size_t)c * QKVC + 2 * C_;
    double w0 = (double)wp[t];
    double w1 = (double)wp[t + 256];
    double w2 = (double)wp[t + 512];
#pragma unroll
    for (int r = 0; r < 8; r++) {
      double xv = xr[r][c];
      acc[r][0] += xv * w0; acc[r][1] += xv * w1; acc[r][2] += xv * w2;
    }
  }
  for (int r = 0; r < 8; r++) {
    double p = acc[r][0] * acc[r][0] + acc[r][1] * acc[r][1] + acc[r][2] * acc[r][2];
    double s = blockReduceSumD(p, scr, 4);
    if (t == 0) {
      double pol = (double)policy[r0 + r];
      vnorm2[r0 + r] = s * pol * pol;
    }
  }
}

// ---------------- row-0 softmax fp64 (in place) ----------------
__global__ __launch_bounds__(256) void softmax0_kernel(
    double* __restrict__ l64, const float* __restrict__ policy) {
  int bh = blockIdx.x;
  int b = bh / H_;
  double* lp = l64 + (size_t)bh * N_;
  __shared__ double scr[8];
  int t = threadIdx.x;
  double mx = -1e300;
  for (int n = t; n < N_; n += 256) mx = fmax(mx, lp[n]);
  mx = blockReduceMaxD(mx, scr, 4);
  double ssum = 0.0;
  for (int n = t; n < N_; n += 256) {
    double pol = (double)policy[b * N_ + n];
    double w = (n == 0) ? 1.0 : pol;
    double e = exp(lp[n] - mx) * w;
    lp[n] = e;
    ssum += e;
  }
  ssum = blockReduceSumD(ssum, scr, 4);
  double denom = ssum + SMEPS;
  double addc = SMEPS / (double)N_;
  for (int n = t; n < N_; n += 256) lp[n] = (lp[n] + addc) / denom;
}

// ---------------- selection fp64, paranoid-simple ----------------
__global__ __launch_bounds__(1024) void select_kernel(
    const double* __restrict__ p0, const double* __restrict__ vnorm2,
    int* __restrict__ selidx, float* __restrict__ poln, float* __restrict__ out_pol) {
  int b = blockIdx.x;
  int t = threadIdx.x;
  __shared__ double sigv[MSEL];
  __shared__ double svals[MSEL];
  __shared__ double nc[MSEL];
  __shared__ int    ord[MSEL];
  __shared__ int    pick[MSEL];
  __shared__ int    spick[MSEL];
  __shared__ int    uq[MSEL];
  __shared__ int    suq[MSEL];
  __shared__ double sh_ys;

  if (t < MSEL) {
    int n = t + 1;
    double s = 0.0;
#pragma unroll
    for (int h = 0; h < H_; h++) s += p0[(size_t)(b * H_ + h) * N_ + n];
    sigv[t] = s * sqrt(vnorm2[b * N_ + n]);
  }
  __syncthreads();
  if (t < MSEL) {
    double v = sigv[t];
    int rank = 0;
    for (int i = 0; i < MSEL; i++) {
      double vi = sigv[i];
      rank += (vi < v) || (vi == v && i < t);
    }
    ord[rank] = t;
    svals[rank] = v;
  }
  __syncthreads();
  if (t == 0) {
    double a = 0.0;
    for (int i = 0; i < MSEL; i++) { a += svals[i]; svals[i] = a; }
  }
  __syncthreads();
  {
    double c0 = svals[0], cN = svals[MSEL - 1];
    if (t < MSEL) nc[t] = (svals[t] - c0) / (cN - c0);
  }
  __syncthreads();
  if (t == 0) {
    double m = 1e300;
    for (int i = 0; i < MSEL; i++) {
      double v = nc[i];
      if (v == 0.0) v += 100000000.0;
      m = fmin(m, v);
    }
    sh_ys = m;
  }
  __syncthreads();
  if (t < MSEL) {
    double s = sh_ys;
    double ysj = (t == MSEL - 1) ? 1.0 : (double)t / 783.0;
    double y = s + (ysj * 783.0 - s * (double)t) / 783.0;
    double bd = 1e300;
    int bi = 0;
    for (int i = 0; i < MSEL; i++) {
      double d = fabs(y - nc[i]);
      if (d < bd) { bd = d; bi = i; }
    }
    pick[t] = bi;
  }
  __syncthreads();
  if (t < MSEL) {
    int p = pick[t];
    int rank = 0;
    for (int i = 0; i < MSEL; i++) {
      int pi = pick[i];
      rank += (pi < p) || (pi == p && i < t);
    }
    spick[rank] = p;
  }
  __syncthreads();
  if (t < MSEL) {
    int s = spick[t];
    int nxt = (t < MSEL - 1) ? spick[t + 1] : 1;
    uq[t] = (nxt == s) ? MSEL : s;
  }
  __syncthreads();
  if (t < MSEL) {
    int u = uq[t];
    int rank = 0;
    for (int i = 0; i < MSEL; i++) {
      int ui = uq[i];
      rank += (ui < u) || (ui == u && i < t);
    }
    suq[rank] = u;
  }
  __syncthreads();
  if (t < NT_) {
    int sel, polI;
    if (t == 0) { sel = 0; polI = 1; }
    else {
      int ut = suq[t - 1];
      polI = (ut != MSEL) ? 1 : 0;
      sel = polI ? (ord[ut] + 1) : -1;
    }
    selidx[b * NT_ + t] = sel;
    poln[b * NT_ + t] = (float)polI;
    out_pol[b * NT_ + t] = (float)polI;
  }
}

// ---------------- Phase A: S = scale * Q_sel @ K^T  per (b,h) ----------------
__global__ __launch_bounds__(256) void qk_kernel(
    const float* __restrict__ qkv, const int* __restrict__ selidx,
    float* __restrict__ S) {
  int bh = blockIdx.z;
  int b = bh / H_, h = bh % H_;
  int j0 = blockIdx.y * 64;
  int n0 = blockIdx.x * 64;
  int t = threadIdx.x;
  __shared__ float Qs[64][68];
  __shared__ float Ks[64][68];
  int lm = t >> 2;
  int kb = (t & 3) * 16;
  {
    int j = j0 + lm;
    int r = (j < NT_) ? selidx[b * NT_ + j] : -1;
    if (r < 0) r = 0;
    const float* qp = qkv + (size_t)(b * N_ + r) * QKVC + h * DH_ + kb;
    float4 v0 = *(const float4*)(qp + 0);
    float4 v1 = *(const float4*)(qp + 4);
    float4 v2 = *(const float4*)(qp + 8);
    float4 v3 = *(const float4*)(qp + 12);
    Qs[kb + 0][lm] = v0.x; Qs[kb + 1][lm] = v0.y; Qs[kb + 2][lm] = v0.z; Qs[kb + 3][lm] = v0.w;
    Qs[kb + 4][lm] = v1.x; Qs[kb + 5][lm] = v1.y; Qs[kb + 6][lm] = v1.z; Qs[kb + 7][lm] = v1.w;
    Qs[kb + 8][lm] = v2.x; Qs[kb + 9][lm] = v2.y; Qs[kb +10][lm] = v2.z; Qs[kb +11][lm] = v2.w;
    Qs[kb +12][lm] = v3.x; Qs[kb +13][lm] = v3.y; Qs[kb +14][lm] = v3.z; Qs[kb +15][lm] = v3.w;
  }
  {
    int n = n0 + lm;
    bool ok = n < N_;
    const float* kp = qkv + (size_t)(b * N_ + (ok ? n : 0)) * QKVC + C_ + h * DH_ + kb;
    float4 v0 = ok ? *(const float4*)(kp + 0)  : make_float4(0, 0, 0, 0);
    float4 v1 = ok ? *(const float4*)(kp + 4)  : make_float4(0, 0, 0, 0);
    float4 v2 = ok ? *(const float4*)(kp + 8)  : make_float4(0, 0, 0, 0);
    float4 v3 = ok ? *(const float4*)(kp + 12) : make_float4(0, 0, 0, 0);
    Ks[kb + 0][lm] = v0.x; Ks[kb + 1][lm] = v0.y; Ks[kb + 2][lm] = v0.z; Ks[kb + 3][lm] = v0.w;
    Ks[kb + 4][lm] = v1.x; Ks[kb + 5][lm] = v1.y; Ks[kb + 6][lm] = v1.z; Ks[kb + 7][lm] = v1.w;
    Ks[kb + 8][lm] = v2.x; Ks[kb + 9][lm] = v2.y; Ks[kb +10][lm] = v2.z; Ks[kb +11][lm] = v2.w;
    Ks[kb +12][lm] = v3.x; Ks[kb +13][lm] = v3.y; Ks[kb +14][lm] = v3.z; Ks[kb +15][lm] = v3.w;
  }
  __syncthreads();
  int tm = (t >> 4) << 2, tn = (t & 15) << 2;
  float acc[4][4] = {{0.f}};
#pragma unroll 16
  for (int k = 0; k < 64; k++) {
    float a0 = Qs[k][tm + 0], a1 = Qs[k][tm + 1], a2 = Qs[k][tm + 2], a3 = Qs[k][tm + 3];
    float b0 = Ks[k][tn + 0], b1 = Ks[k][tn + 1], b2 = Ks[k][tn + 2], b3 = Ks[k][tn + 3];
    acc[0][0] += a0 * b0; acc[0][1] += a0 * b1; acc[0][2] += a0 * b2; acc[0][3] += a0 * b3;
    acc[1][0] += a1 * b0; acc[1][1] += a1 * b1; acc[1][2] += a1 * b2; acc[1][3] += a1 * b3;
    acc[2][0] += a2 * b0; acc[2][1] += a2 * b1; acc[2][2] += a2 * b2; acc[2][3] += a2 * b3;
    acc[3][0] += a3 * b0; acc[3][1] += a3 * b1; acc[3][2] += a3 * b2; acc[3][3] += a3 * b3;
  }
#pragma unroll
  for (int i = 0; i < 4; i++) {
    int j = j0 + tm + i;
    if (j >= NT_) continue;
#pragma unroll
    for (int jj = 0; jj < 4; jj++) {
      int n = n0 + tn + jj;
      if (n >= N_) continue;
      S[((size_t)bh * NT_ + j) * N_ + n] = acc[i][jj] * SCALE_F;
    }
  }
}

// ---------------- Phase B: softmax-with-policy over S rows ----------------
__global__ __launch_bounds__(256) void smax_kernel(
    float* __restrict__ S, const int* __restrict__ selidx,
    const float* __restrict__ policy) {
  int row = blockIdx.x;
  int b = row / NT_;
  int j = row - b * NT_;
  int r = selidx[row];
  int t = threadIdx.x;
  __shared__ float buf[N_];
  __shared__ float fscr[8];
  for (int h = 0; h < H_; h++) {
    float* sp = S + ((size_t)(b * H_ + h) * NT_ + j) * N_;
    float m = -1e30f;
    for (int n = t; n < N_; n += 256) { float v = sp[n]; buf[n] = v; m = fmaxf(m, v); }
    m = blockReduceMaxF(m, fscr, 4);
    float p = 0.f;
    for (int n = t; n < N_; n += 256) {
      float pol = policy[b * N_ + n];
      float w = (n == r) ? 1.0f : pol;
      float e = expf(buf[n] - m) * w;
      buf[n] = e;
      p += e;
    }
    float Ssum = blockReduceSumF(p, fscr, 4);
    float denom = Ssum + 1e-6f;
    float addc = 1e-6f / (float)N_;
    for (int n = t; n < N_; n += 256) sp[n] = (buf[n] + addc) / denom;
    __syncthreads();
  }
}

// ---------------- Phase C: attn_bf = P @ V  per (b,h), bf16 out ------------------
__global__ __launch_bounds__(256) void pv_kernel(
    const float* __restrict__ S, const float* __restrict__ qkv,
    bf16* __restrict__ attn_bf) {
  int bh = blockIdx.z;
  int b = bh / H_, h = bh % H_;
  int j0 = blockIdx.y * 64;
  int t = threadIdx.x;
  __shared__ float Ps[16][68];
  __shared__ float Vs[16][68];
  int tm = (t >> 4) << 2, tn = (t & 15) << 2;
  float acc[4][4] = {{0.f}};
  int lm = t >> 2;
  int lk = (t & 3) << 2;
  int vd = t & 63;
  int vk4 = (t >> 6) * 4;
  for (int k0 = 0; k0 < N_; k0 += 16) {
#pragma unroll
    for (int i = 0; i < 4; i++) {
      int kk = k0 + lk + i;
      float v = 0.f;
      if (j0 + lm < NT_ && kk < N_)
        v = S[((size_t)bh * NT_ + j0 + lm) * N_ + kk];
      Ps[lk + i][lm] = v;
    }
#pragma unroll
    for (int i = 0; i < 4; i++) {
      int kk = k0 + vk4 + i;
      float v = 0.f;
      if (kk < N_)
        v = qkv[(size_t)(b * N_ + kk) * QKVC + 2 * C_ + h * DH_ + vd];
      Vs[vk4 + i][vd] = v;
    }
    __syncthreads();
#pragma unroll
    for (int k = 0; k < 16; k++) {
      float a0 = Ps[k][tm + 0], a1 = Ps[k][tm + 1], a2 = Ps[k][tm + 2], a3 = Ps[k][tm + 3];
      float b0 = Vs[k][tn + 0], b1 = Vs[k][tn + 1], b2 = Vs[k][tn + 2], b3 = Vs[k][tn + 3];
      acc[0][0] += a0 * b0; acc[0][1] += a0 * b1; acc[0][2] += a0 * b2; acc[0][3] += a0 * b3;
      acc[1][0] += a1 * b0; acc[1][1] += a1 * b1; acc[1][2] += a1 * b2; acc[1][3] += a1 * b3;
      acc[2][0] += a2 * b0; acc[2][1] += a2 * b1; acc[2][2] += a2 * b2; acc[2][3] += a2 * b3;
      acc[3][0] += a3 * b0; acc[3][1] += a3 * b1; acc[3][2] += a3 * b2; acc[3][3] += a3 * b3;
    }
    __syncthreads();
  }
#pragma unroll
  for (int i = 0; i < 4; i++) {
    int m = j0 + tm + i;
    if (m >= NT_) continue;
#pragma unroll
    for (int jj = 0; jj < 4; jj++) {
      attn_bf[(size_t)(b * NT_ + m) * C_ + h * DH_ + tn + jj] =
          __float2bfloat16(acc[i][jj]);
    }
  }
}

// ---------------- epilogues ----------------
__global__ __launch_bounds__(256) void e2_kernel(
    const float* __restrict__ cbuf, const float* __restrict__ poln,
    const int* __restrict__ selidx, const float* __restrict__ x, float* __restrict__ x2) {
  int row = blockIdx.x;
  int t = threadIdx.x;
  int b = row / NT_;
  int r = selidx[row];
  float pn = poln[row];
  for (int i = t; i < C_; i += 256) {
    float sx = (r >= 0) ? x[(size_t)(b * N_ + r) * C_ + i] : 0.f;
    x2[(size_t)row * C_ + i] = sx + cbuf[(size_t)row * C_ + i] * pn;
  }
}

__global__ __launch_bounds__(256) void ln2_kernel(
    const float* __restrict__ xin, const float* __restrict__ w, const float* __restrict__ b,
    bf16* __restrict__ xoutb) {
  int row = blockIdx.x;
  int t = threadIdx.x;
  __shared__ float scr[8];
  const float* xr = xin + (size_t)row * C_;
  float vals[3];
#pragma unroll
  for (int i = 0; i < 3; i++) vals[i] = xr[t + i * 256];
  float s = vals[0] + vals[1] + vals[2];
  s = blockReduceSumF(s, scr, 4);
  float mean = s / (float)C_;
  float vs = 0.f;
#pragma unroll
  for (int i = 0; i < 3; i++) { float d = vals[i] - mean; vs += d * d; }
  vs = blockReduceSumF(vs, scr, 4);
  float sd = sqrtf(vs / (float)C_ + 1e-5f);
#pragma unroll
  for (int i = 0; i < 3; i++) {
    int c = t + i * 256;
    xoutb[(size_t)row * C_ + c] =
        __float2bfloat16((vals[i] - mean) / sd * w[c] + b[c]);
  }
}

DEV float gelu_exact(float v) { return 0.5f * v * (1.0f + erff(v * 0.70710678118654752f)); }

__global__ __launch_bounds__(256) void gelu_kernel(
    const float* __restrict__ h, bf16* __restrict__ hb) {
  size_t i = (size_t)blockIdx.x * 256 + threadIdx.x;
  float4 v = ((const float4*)h)[i];
  ushort4 o;
  o.x = __hip_bfloat16_raw(__float2bfloat16(gelu_exact(v.x))).x;
  o.y = __hip_bfloat16_raw(__float2bfloat16(gelu_exact(v.y))).x;
  o.z = __hip_bfloat16_raw(__float2bfloat16(gelu_exact(v.z))).x;
  o.w = __hip_bfloat16_raw(__float2bfloat16(gelu_exact(v.w))).x;
  ((ushort4*)hb)[i] = o;
}

__global__ __launch_bounds__(256) void e4_kernel(
    const float* __restrict__ x2, const float* __restrict__ cbuf,
    const float* __restrict__ poln, float* __restrict__ out) {
  int row = blockIdx.x;
  int t = threadIdx.x;
  float pn = poln[row];
  for (int i = t; i < C_; i += 256) {
    float v = x2[(size_t)row * C_ + i] + cbuf[(size_t)row * C_ + i] * pn;
    out[(size_t)row * C_ + i] = v;
  }
}

// ---------------- launcher ----------------
extern "C" void kernel_launch(void* const* d_in, const int* in_sizes, int n_in,
                              void* d_out, int out_size, void* d_ws, size_t ws_size,
                              hipStream_t stream) {
  const float* x      = (const float*)d_in[0];
  const float* policy = (const float*)d_in[1];
  const float* n1w    = (const float*)d_in[2];
  const float* n1b    = (const float*)d_in[3];
  const float* qkvw   = (const float*)d_in[4];
  const float* projw  = (const float*)d_in[5];
  const float* projb  = (const float*)d_in[6];
  const float* n2w    = (const float*)d_in[7];
  const float* n2b    = (const float*)d_in[8];
  const float* fc1w   = (const float*)d_in[9];
  const float* fc1b   = (const float*)d_in[10];
  const float* fc2w   = (const float*)d_in[11];
  const float* fc2b   = (const float*)d_in[12];

  char* ws = (char*)d_ws;
  size_t off = 0;
  auto alloc = [&](size_t bytes) {
    size_t o = off;
    off += (bytes + 255) & ~(size_t)255;
    return o;
  };

  double* xn64    = (double*)(ws + alloc((size_t)BN * C_ * 8));
  bf16*   xnb     = (bf16*)(ws + alloc((size_t)BN * C_ * 2));
  float*  qkv32   = (float*)(ws + alloc((size_t)BN * QKVC * 4));
  double* vnorm2  = (double*)(ws + alloc((size_t)BN * 8));
  double* q064    = (double*)(ws + alloc((size_t)B_ * C_ * 8));
  double* g64     = (double*)(ws + alloc((size_t)B_ * H_ * C_ * 8));
  double* l64     = (double*)(ws + alloc((size_t)B_ * H_ * N_ * 8));
  int*    selidx  = (int*)(ws + alloc((size_t)BT * 4));
  float*  poln    = (float*)(ws + alloc((size_t)BT * 4));
  bf16*   attn_bf = (bf16*)(ws + alloc((size_t)BT * C_ * 2));
  float*  cbuf    = (float*)(ws + alloc((size_t)BT * C_ * 4));
  float*  x2      = (float*)(ws + alloc((size_t)BT * C_ * 4));
  bf16*   qkvw_t  = (bf16*)(ws + alloc((size_t)QKVC * C_ * 2));
  bf16*   projw_t = (bf16*)(ws + alloc((size_t)C_ * C_ * 2));
  bf16*   fc1w_t  = (bf16*)(ws + alloc((size_t)4 * C_ * C_ * 2));
  bf16*   fc2w_t  = (bf16*)(ws + alloc((size_t)C_ * 4 * C_ * 2));

  // UNION: Sbuf (dead after pv) overlaps xn2_bf + h32 + h_bf (written after pv).
  size_t S_bytes    = (size_t)B_ * H_ * NT_ * N_ * 4;                 // ~118 MB
  size_t xn2b_bytes = ((size_t)BT * C_ * 2 + 255) & ~(size_t)255;
  size_t h32_bytes  = ((size_t)BT * 4 * C_ * 4 + 255) & ~(size_t)255;
  size_t hbf_bytes  = (size_t)BT * 4 * C_ * 2;
  size_t late_bytes = xn2b_bytes + h32_bytes + hbf_bytes;
  size_t union_bytes = S_bytes > late_bytes ? S_bytes : late_bytes;
  char* ub    = ws + alloc(union_bytes);
  float* Sbuf  = (float*)ub;
  bf16*  xn2b  = (bf16*)ub;
  float* h32   = (float*)(ub + xn2b_bytes);
  bf16*  h_bf  = (bf16*)(ub + xn2b_bytes + h32_bytes);
  if (off > ws_size) return;

  float* out_x = (float*)d_out;
  float* out_p = out_x + (size_t)BT * C_;

  // weight transposes (fp32 -> bf16 [N][K])
  transpose_bf16<<<dim3(QKVC / 32, C_ / 32), 256, 0, stream>>>(qkvw, qkvw_t, C_, QKVC);
  transpose_bf16<<<dim3(C_ / 32, C_ / 32), 256, 0, stream>>>(projw, projw_t, C_, C_);
  transpose_bf16<<<dim3(4 * C_ / 32, C_ / 32), 256, 0, stream>>>(fc1w, fc1w_t, C_, 4 * C_);
  transpose_bf16<<<dim3(C_ / 32, 4 * C_ / 32), 256, 0, stream>>>(fc2w, fc2w_t, 4 * C_, C_);

  ln1_kernel<<<BN, 256, 0, stream>>>(x, n1w, n1b, xn64, xnb);

  {
    dim3 g(QKVC / 64, (BN + 63) / 64);
    gemm_bf16<<<g, 256, 0, stream>>>(xnb, qkvw_t, qkv32, nullptr, policy, BN, C_, QKVC);
  }

  // fp64 scoring path
  q0_kernel<<<B_, 256, 0, stream>>>(xn64, qkvw, policy, q064);
  g_kernel<<<B_ * H_, 256, 0, stream>>>(q064, qkvw, g64);
  logits_kernel<<<BN, 256, 0, stream>>>(xn64, g64, policy, l64);
  vnorm_kernel<<<BN / 8, 256, 0, stream>>>(xn64, qkvw, policy, vnorm2);
  softmax0_kernel<<<B_ * H_, 256, 0, stream>>>(l64, policy);
  select_kernel<<<B_, 1024, 0, stream>>>(l64, vnorm2, selidx, poln, out_p);

  // attention
  {
    dim3 g((N_ + 63) / 64, (NT_ + 63) / 64, B_ * H_);
    qk_kernel<<<g, 256, 0, stream>>>(qkv32, selidx, Sbuf);
  }
  smax_kernel<<<BT, 256, 0, stream>>>(Sbuf, selidx, policy);
  {
    dim3 g(1, (NT_ + 63) / 64, B_ * H_);
    pv_kernel<<<g, 256, 0, stream>>>(Sbuf, qkv32, attn_bf);
  }

  {
    dim3 g(C_ / 64, (BT + 63) / 64);
    gemm_bf16<<<g, 256, 0, stream>>>(attn_bf, projw_t, cbuf, projb, nullptr, BT, C_, C_);
  }
  e2_kernel<<<BT, 256, 0, stream>>>(cbuf, poln, selidx, x, x2);
  ln2_kernel<<<BT, 256, 0, stream>>>(x2, n2w, n2b, xn2b);
  {
    dim3 g(4 * C_ / 64, (BT + 63) / 64);
    gemm_bf16<<<g, 256, 0, stream>>>(xn2b, fc1w_t, h32, fc1b, nullptr, BT, C_, 4 * C_);
  }
  gelu_kernel<<<(BT * 4 * C_) / 1024, 256, 0, stream>>>(h32, h_bf);
  {
    dim3 g(C_ / 64, (BT + 63) / 64);
    gemm_bf16<<<g, 256, 0, stream>>>(h_bf, fc2w_t, cbuf, fc2b, nullptr, BT, 4 * C_, C_);
  }
  e4_kernel<<<BT, 256, 0, stream>>>(x2, cbuf, poln, out_x);
}

// Round 12
// 1203.622 us; speedup vs baseline: 3.6068x; 1.0461x over previous
//
#include <hip/hip_runtime.h>
#include <hip/hip_bf16.h>
#include <float.h>
#include <math.h>
#include <stdint.h>

constexpr int B_   = 8;
constexpr int N_   = 785;
constexpr int C_   = 768;
constexpr int H_   = 12;
constexpr int DH_  = 64;
constexpr int NT_  = 393;
constexpr int QKVC = 3 * C_;   // 2304
constexpr int BN   = B_ * N_;  // 6280
constexpr int BT   = B_ * NT_; // 3144
constexpr int MSEL = N_ - 1;   // 784
constexpr float  SCALE_F = 0.125f;
constexpr double LNEPS   = 1e-5;
constexpr double SMEPS   = 1e-6;

#define DEV static __device__ __forceinline__

typedef __hip_bfloat16 bf16;
typedef __attribute__((ext_vector_type(8))) short frag8;
typedef __attribute__((ext_vector_type(4))) float facc4;

// ---------------- block reductions ----------------
DEV double blockReduceSumD(double v, double* scratch, int nw) {
#pragma unroll
  for (int o = 32; o; o >>= 1) v += __shfl_xor(v, o);
  int lane = threadIdx.x & 63, wid = threadIdx.x >> 6;
  __syncthreads();
  if (lane == 0) scratch[wid] = v;
  __syncthreads();
  double r = scratch[0];
  for (int i = 1; i < nw; i++) r += scratch[i];
  return r;
}
DEV double blockReduceMaxD(double v, double* scratch, int nw) {
#pragma unroll
  for (int o = 32; o; o >>= 1) v = fmax(v, __shfl_xor(v, o));
  int lane = threadIdx.x & 63, wid = threadIdx.x >> 6;
  __syncthreads();
  if (lane == 0) scratch[wid] = v;
  __syncthreads();
  double r = scratch[0];
  for (int i = 1; i < nw; i++) r = fmax(r, scratch[i]);
  return r;
}
DEV float blockReduceSumF(float v, float* scratch, int nw) {
#pragma unroll
  for (int o = 32; o; o >>= 1) v += __shfl_xor(v, o);
  int lane = threadIdx.x & 63, wid = threadIdx.x >> 6;
  __syncthreads();
  if (lane == 0) scratch[wid] = v;
  __syncthreads();
  float r = scratch[0];
  for (int i = 1; i < nw; i++) r += scratch[i];
  return r;
}
DEV float blockReduceMaxF(float v, float* scratch, int nw) {
#pragma unroll
  for (int o = 32; o; o >>= 1) v = fmaxf(v, __shfl_xor(v, o));
  int lane = threadIdx.x & 63, wid = threadIdx.x >> 6;
  __syncthreads();
  if (lane == 0) scratch[wid] = v;
  __syncthreads();
  float r = scratch[0];
  for (int i = 1; i < nw; i++) r = fmaxf(r, scratch[i]);
  return r;
}

// ---------------- LN1: x(f32) -> xn64 (fp64 scoring) + xn_bf (bf16 value) --------
__global__ __launch_bounds__(256) void ln1_kernel(
    const float* __restrict__ x, const float* __restrict__ w, const float* __restrict__ b,
    double* __restrict__ xn64, bf16* __restrict__ xnb) {
  int row = blockIdx.x;
  int t = threadIdx.x;
  __shared__ double scr[8];
  const float* xr = x + (size_t)row * C_;
  double vals[3];
#pragma unroll
  for (int i = 0; i < 3; i++) vals[i] = (double)xr[t + i * 256];
  double s = vals[0] + vals[1] + vals[2];
  s = blockReduceSumD(s, scr, 4);
  double mean = s / (double)C_;
  double vs = 0.0;
#pragma unroll
  for (int i = 0; i < 3; i++) { double d = vals[i] - mean; vs += d * d; }
  vs = blockReduceSumD(vs, scr, 4);
  double inv = 1.0 / sqrt(vs / (double)C_ + LNEPS);
#pragma unroll
  for (int i = 0; i < 3; i++) {
    int c = t + i * 256;
    double o = (vals[i] - mean) * inv * (double)w[c] + (double)b[c];
    xn64[(size_t)row * C_ + c] = o;
    xnb[(size_t)row * C_ + c] = __float2bfloat16((float)o);
  }
}

// ---------------- weight transpose+convert: W[K][N] f32 -> Wt[N][K] bf16 ---------
__global__ __launch_bounds__(256) void transpose_bf16(
    const float* __restrict__ W, bf16* __restrict__ Wt, int K, int N) {
  __shared__ float tile[32][33];
  int k0 = blockIdx.y * 32, n0 = blockIdx.x * 32;
  int tx = threadIdx.x & 31, ty = threadIdx.x >> 5;
  for (int i = ty; i < 32; i += 8) {
    int k = k0 + i, n = n0 + tx;
    tile[i][tx] = (k < K && n < N) ? W[(size_t)k * N + n] : 0.f;
  }
  __syncthreads();
  for (int i = ty; i < 32; i += 8) {
    int n = n0 + i, k = k0 + tx;
    if (n < N && k < K) Wt[(size_t)n * K + k] = __float2bfloat16(tile[tx][i]);
  }
}

// ---------------- bf16 MFMA GEMM: C[MxN]f32 = A[MxK]bf16 @ Wt[NxK]bf16 -----------
__global__ __launch_bounds__(256) void gemm_bf16(
    const bf16* __restrict__ A, const bf16* __restrict__ Bt,
    float* __restrict__ Cc, const float* __restrict__ bias,
    const float* __restrict__ rowscale, int M, int K, int Ncols) {
  __shared__ short As[64][40];
  __shared__ short Bs[64][40];
  const short* Ap = (const short*)A;
  const short* Bp = (const short*)Bt;
  int t = threadIdx.x;
  int n0 = blockIdx.x * 64;
  int m0 = blockIdx.y * 64;
  int w = t >> 6, l = t & 63;
  int srow = t >> 2;
  int koff = (t & 3) * 8;
  facc4 acc[4] = {{0, 0, 0, 0}, {0, 0, 0, 0}, {0, 0, 0, 0}, {0, 0, 0, 0}};
  int frow = (l & 15);
  int fk = (l >> 4) * 8;
  for (int k0 = 0; k0 < K; k0 += 32) {
    {
      int4 av = make_int4(0, 0, 0, 0);
      if (m0 + srow < M)
        av = *(const int4*)(Ap + (size_t)(m0 + srow) * K + k0 + koff);
      *(int4*)(&As[srow][koff]) = av;
      int4 bv = *(const int4*)(Bp + (size_t)(n0 + srow) * K + k0 + koff);
      *(int4*)(&Bs[srow][koff]) = bv;
    }
    __syncthreads();
    frag8 a = *(frag8*)(&As[w * 16 + frow][fk]);
#pragma unroll
    for (int nt = 0; nt < 4; nt++) {
      frag8 bfr = *(frag8*)(&Bs[nt * 16 + frow][fk]);
      acc[nt] = __builtin_amdgcn_mfma_f32_16x16x32_bf16(a, bfr, acc[nt], 0, 0, 0);
    }
    __syncthreads();
  }
#pragma unroll
  for (int nt = 0; nt < 4; nt++) {
#pragma unroll
    for (int reg = 0; reg < 4; reg++) {
      int row = m0 + w * 16 + (l >> 4) * 4 + reg;
      int col = n0 + nt * 16 + (l & 15);
      if (row < M) {
        float v = acc[nt][reg];
        if (bias) v += bias[col];
        if (rowscale) v *= rowscale[row];
        Cc[(size_t)row * Ncols + col] = v;
      }
    }
  }
}

// ---------------- q0 (row-0 query, fp64) ----------------
__global__ __launch_bounds__(256) void q0_kernel(
    const double* __restrict__ xn64, const float* __restrict__ qkvw,
    const float* __restrict__ policy, double* __restrict__ q064) {
  int b = blockIdx.x;
  int t = threadIdx.x;
  __shared__ double x0[C_];
  for (int i = t; i < C_; i += 256) x0[i] = xn64[(size_t)(b * N_) * C_ + i];
  __syncthreads();
  double pol = (double)policy[b * N_];
  for (int j = t; j < C_; j += 256) {
    double a = 0.0;
    for (int c = 0; c < C_; c++) a += x0[c] * (double)qkvw[(size_t)c * QKVC + j];
    q064[b * C_ + j] = a * pol;
  }
}

// ---------------- g[b,h,c] (fp64) ----------------
__global__ __launch_bounds__(256) void g_kernel(
    const double* __restrict__ q064, const float* __restrict__ qkvw,
    double* __restrict__ g64) {
  int bh = blockIdx.x;
  int b = bh / H_, h = bh % H_;
  int t = threadIdx.x;
  __shared__ double qh[DH_];
  if (t < DH_) qh[t] = q064[b * C_ + h * DH_ + t];
  __syncthreads();
  for (int c = t; c < C_; c += 256) {
    const float* wp = qkvw + (size_t)c * QKVC + C_ + h * DH_;
    double a = 0.0;
#pragma unroll 8
    for (int d = 0; d < DH_; d++) a += qh[d] * (double)wp[d];
    g64[(size_t)bh * C_ + c] = a;
  }
}

// ---------------- row-0 logits fp64: wave-per-head, shuffle reduce ---------------
__global__ __launch_bounds__(256) void logits_kernel(
    const double* __restrict__ xn64, const double* __restrict__ g64,
    const float* __restrict__ policy, double* __restrict__ l64) {
  int row = blockIdx.x;
  int b = row / N_;
  int n = row % N_;
  int t = threadIdx.x;
  int w = t >> 6, lane = t & 63;
  __shared__ double xr[C_];
  for (int i = t; i < C_; i += 256) xr[i] = xn64[(size_t)row * C_ + i];
  __syncthreads();
  double pol = (double)policy[row];
#pragma unroll
  for (int hh = 0; hh < 3; hh++) {
    int h = w + hh * 4;
    const double* gp = g64 + (size_t)(b * H_ + h) * C_;
    double p = 0.0;
#pragma unroll 4
    for (int i = lane; i < C_; i += 64) p += xr[i] * gp[i];
#pragma unroll
    for (int o = 32; o; o >>= 1) p += __shfl_xor(p, o);
    if (lane == 0) l64[(size_t)(b * H_ + h) * N_ + n] = 0.125 * pol * p;
  }
}

// ---------------- ||v||^2 fp64: 4 rows/block, double2 LDS, c-unroll x2 -----------
__global__ __launch_bounds__(256) void vnorm_kernel(
    const double* __restrict__ xn64, const float* __restrict__ qkvw,
    const float* __restrict__ policy, double* __restrict__ vnorm2) {
  __shared__ double xr[4][C_];  // 24576 B
  __shared__ double scr[8];
  int r0 = blockIdx.x * 4;
  int t = threadIdx.x;
  for (int i = t; i < 4 * C_; i += 256)
    xr[i / C_][i % C_] = xn64[(size_t)(r0 + i / C_) * C_ + (i % C_)];
  __syncthreads();
  double acc[4][3] = {};
  for (int c = 0; c < C_; c += 2) {
    const float* wp0 = qkvw + (size_t)c * QKVC + 2 * C_;
    const float* wp1 = wp0 + QKVC;
    double w00 = (double)wp0[t], w01 = (double)wp0[t + 256], w02 = (double)wp0[t + 512];
    double w10 = (double)wp1[t], w11 = (double)wp1[t + 256], w12 = (double)wp1[t + 512];
#pragma unroll
    for (int r = 0; r < 4; r++) {
      double2 xv = *(const double2*)(&xr[r][c]);
      acc[r][0] += xv.x * w00; acc[r][1] += xv.x * w01; acc[r][2] += xv.x * w02;
      acc[r][0] += xv.y * w10; acc[r][1] += xv.y * w11; acc[r][2] += xv.y * w12;
    }
  }
  for (int r = 0; r < 4; r++) {
    double p = acc[r][0] * acc[r][0] + acc[r][1] * acc[r][1] + acc[r][2] * acc[r][2];
    double s = blockReduceSumD(p, scr, 4);
    if (t == 0) {
      double pol = (double)policy[r0 + r];
      vnorm2[r0 + r] = s * pol * pol;
    }
  }
}

// ---------------- row-0 softmax fp64 (in place) ----------------
__global__ __launch_bounds__(256) void softmax0_kernel(
    double* __restrict__ l64, const float* __restrict__ policy) {
  int bh = blockIdx.x;
  int b = bh / H_;
  double* lp = l64 + (size_t)bh * N_;
  __shared__ double scr[8];
  int t = threadIdx.x;
  double mx = -1e300;
  for (int n = t; n < N_; n += 256) mx = fmax(mx, lp[n]);
  mx = blockReduceMaxD(mx, scr, 4);
  double ssum = 0.0;
  for (int n = t; n < N_; n += 256) {
    double pol = (double)policy[b * N_ + n];
    double w = (n == 0) ? 1.0 : pol;
    double e = exp(lp[n] - mx) * w;
    lp[n] = e;
    ssum += e;
  }
  ssum = blockReduceSumD(ssum, scr, 4);
  double denom = ssum + SMEPS;
  double addc = SMEPS / (double)N_;
  for (int n = t; n < N_; n += 256) lp[n] = (lp[n] + addc) / denom;
}

// ---------------- selection fp64, paranoid-simple ----------------
__global__ __launch_bounds__(1024) void select_kernel(
    const double* __restrict__ p0, const double* __restrict__ vnorm2,
    int* __restrict__ selidx, float* __restrict__ poln, float* __restrict__ out_pol) {
  int b = blockIdx.x;
  int t = threadIdx.x;
  __shared__ double sigv[MSEL];
  __shared__ double svals[MSEL];
  __shared__ double nc[MSEL];
  __shared__ int    ord[MSEL];
  __shared__ int    pick[MSEL];
  __shared__ int    spick[MSEL];
  __shared__ int    uq[MSEL];
  __shared__ int    suq[MSEL];
  __shared__ double sh_ys;

  if (t < MSEL) {
    int n = t + 1;
    double s = 0.0;
#pragma unroll
    for (int h = 0; h < H_; h++) s += p0[(size_t)(b * H_ + h) * N_ + n];
    sigv[t] = s * sqrt(vnorm2[b * N_ + n]);
  }
  __syncthreads();
  if (t < MSEL) {
    double v = sigv[t];
    int rank = 0;
    for (int i = 0; i < MSEL; i++) {
      double vi = sigv[i];
      rank += (vi < v) || (vi == v && i < t);
    }
    ord[rank] = t;
    svals[rank] = v;
  }
  __syncthreads();
  if (t == 0) {
    double a = 0.0;
    for (int i = 0; i < MSEL; i++) { a += svals[i]; svals[i] = a; }
  }
  __syncthreads();
  {
    double c0 = svals[0], cN = svals[MSEL - 1];
    if (t < MSEL) nc[t] = (svals[t] - c0) / (cN - c0);
  }
  __syncthreads();
  if (t == 0) {
    double m = 1e300;
    for (int i = 0; i < MSEL; i++) {
      double v = nc[i];
      if (v == 0.0) v += 100000000.0;
      m = fmin(m, v);
    }
    sh_ys = m;
  }
  __syncthreads();
  if (t < MSEL) {
    double s = sh_ys;
    double ysj = (t == MSEL - 1) ? 1.0 : (double)t / 783.0;
    double y = s + (ysj * 783.0 - s * (double)t) / 783.0;
    double bd = 1e300;
    int bi = 0;
    for (int i = 0; i < MSEL; i++) {
      double d = fabs(y - nc[i]);
      if (d < bd) { bd = d; bi = i; }
    }
    pick[t] = bi;
  }
  __syncthreads();
  if (t < MSEL) {
    int p = pick[t];
    int rank = 0;
    for (int i = 0; i < MSEL; i++) {
      int pi = pick[i];
      rank += (pi < p) || (pi == p && i < t);
    }
    spick[rank] = p;
  }
  __syncthreads();
  if (t < MSEL) {
    int s = spick[t];
    int nxt = (t < MSEL - 1) ? spick[t + 1] : 1;
    uq[t] = (nxt == s) ? MSEL : s;
  }
  __syncthreads();
  if (t < MSEL) {
    int u = uq[t];
    int rank = 0;
    for (int i = 0; i < MSEL; i++) {
      int ui = uq[i];
      rank += (ui < u) || (ui == u && i < t);
    }
    suq[rank] = u;
  }
  __syncthreads();
  if (t < NT_) {
    int sel, polI;
    if (t == 0) { sel = 0; polI = 1; }
    else {
      int ut = suq[t - 1];
      polI = (ut != MSEL) ? 1 : 0;
      sel = polI ? (ord[ut] + 1) : -1;
    }
    selidx[b * NT_ + t] = sel;
    poln[b * NT_ + t] = (float)polI;
    out_pol[b * NT_ + t] = (float)polI;
  }
}

// ---------------- Phase A: S = scale * Q_sel @ K^T  per (b,h) ----------------
__global__ __launch_bounds__(256) void qk_kernel(
    const float* __restrict__ qkv, const int* __restrict__ selidx,
    float* __restrict__ S) {
  int bh = blockIdx.z;
  int b = bh / H_, h = bh % H_;
  int j0 = blockIdx.y * 64;
  int n0 = blockIdx.x * 64;
  int t = threadIdx.x;
  __shared__ float Qs[64][68];
  __shared__ float Ks[64][68];
  int lm = t >> 2;
  int kb = (t & 3) * 16;
  {
    int j = j0 + lm;
    int r = (j < NT_) ? selidx[b * NT_ + j] : -1;
    if (r < 0) r = 0;
    const float* qp = qkv + (size_t)(b * N_ + r) * QKVC + h * DH_ + kb;
    float4 v0 = *(const float4*)(qp + 0);
    float4 v1 = *(const float4*)(qp + 4);
    float4 v2 = *(const float4*)(qp + 8);
    float4 v3 = *(const float4*)(qp + 12);
    Qs[kb + 0][lm] = v0.x; Qs[kb + 1][lm] = v0.y; Qs[kb + 2][lm] = v0.z; Qs[kb + 3][lm] = v0.w;
    Qs[kb + 4][lm] = v1.x; Qs[kb + 5][lm] = v1.y; Qs[kb + 6][lm] = v1.z; Qs[kb + 7][lm] = v1.w;
    Qs[kb + 8][lm] = v2.x; Qs[kb + 9][lm] = v2.y; Qs[kb +10][lm] = v2.z; Qs[kb +11][lm] = v2.w;
    Qs[kb +12][lm] = v3.x; Qs[kb +13][lm] = v3.y; Qs[kb +14][lm] = v3.z; Qs[kb +15][lm] = v3.w;
  }
  {
    int n = n0 + lm;
    bool ok = n < N_;
    const float* kp = qkv + (size_t)(b * N_ + (ok ? n : 0)) * QKVC + C_ + h * DH_ + kb;
    float4 v0 = ok ? *(const float4*)(kp + 0)  : make_float4(0, 0, 0, 0);
    float4 v1 = ok ? *(const float4*)(kp + 4)  : make_float4(0, 0, 0, 0);
    float4 v2 = ok ? *(const float4*)(kp + 8)  : make_float4(0, 0, 0, 0);
    float4 v3 = ok ? *(const float4*)(kp + 12) : make_float4(0, 0, 0, 0);
    Ks[kb + 0][lm] = v0.x; Ks[kb + 1][lm] = v0.y; Ks[kb + 2][lm] = v0.z; Ks[kb + 3][lm] = v0.w;
    Ks[kb + 4][lm] = v1.x; Ks[kb + 5][lm] = v1.y; Ks[kb + 6][lm] = v1.z; Ks[kb + 7][lm] = v1.w;
    Ks[kb + 8][lm] = v2.x; Ks[kb + 9][lm] = v2.y; Ks[kb +10][lm] = v2.z; Ks[kb +11][lm] = v2.w;
    Ks[kb +12][lm] = v3.x; Ks[kb +13][lm] = v3.y; Ks[kb +14][lm] = v3.z; Ks[kb +15][lm] = v3.w;
  }
  __syncthreads();
  int tm = (t >> 4) << 2, tn = (t & 15) << 2;
  float acc[4][4] = {{0.f}};
#pragma unroll 16
  for (int k = 0; k < 64; k++) {
    float a0 = Qs[k][tm + 0], a1 = Qs[k][tm + 1], a2 = Qs[k][tm + 2], a3 = Qs[k][tm + 3];
    float b0 = Ks[k][tn + 0], b1 = Ks[k][tn + 1], b2 = Ks[k][tn + 2], b3 = Ks[k][tn + 3];
    acc[0][0] += a0 * b0; acc[0][1] += a0 * b1; acc[0][2] += a0 * b2; acc[0][3] += a0 * b3;
    acc[1][0] += a1 * b0; acc[1][1] += a1 * b1; acc[1][2] += a1 * b2; acc[1][3] += a1 * b3;
    acc[2][0] += a2 * b0; acc[2][1] += a2 * b1; acc[2][2] += a2 * b2; acc[2][3] += a2 * b3;
    acc[3][0] += a3 * b0; acc[3][1] += a3 * b1; acc[3][2] += a3 * b2; acc[3][3] += a3 * b3;
  }
#pragma unroll
  for (int i = 0; i < 4; i++) {
    int j = j0 + tm + i;
    if (j >= NT_) continue;
#pragma unroll
    for (int jj = 0; jj < 4; jj++) {
      int n = n0 + tn + jj;
      if (n >= N_) continue;
      S[((size_t)bh * NT_ + j) * N_ + n] = acc[i][jj] * SCALE_F;
    }
  }
}

// ---------------- Phase B: softmax-with-policy, one block per (bh,j) -------------
__global__ __launch_bounds__(256) void smax_kernel(
    float* __restrict__ S, const int* __restrict__ selidx,
    const float* __restrict__ policy) {
  int idx = blockIdx.x;            // bh * NT + j
  int bh = idx / NT_;
  int j = idx - bh * NT_;
  int b = bh / H_;
  int r = selidx[b * NT_ + j];
  int t = threadIdx.x;
  __shared__ float buf[N_];
  __shared__ float fscr[8];
  float* sp = S + (size_t)idx * N_;
  float m = -1e30f;
  for (int n = t; n < N_; n += 256) { float v = sp[n]; buf[n] = v; m = fmaxf(m, v); }
  m = blockReduceMaxF(m, fscr, 4);
  float p = 0.f;
  for (int n = t; n < N_; n += 256) {
    float pol = policy[b * N_ + n];
    float w = (n == r) ? 1.0f : pol;
    float e = expf(buf[n] - m) * w;
    buf[n] = e;
    p += e;
  }
  float Ssum = blockReduceSumF(p, fscr, 4);
  float denom = Ssum + 1e-6f;
  float addc = 1e-6f / (float)N_;
  for (int n = t; n < N_; n += 256) sp[n] = (buf[n] + addc) / denom;
}

// ---------------- Phase C: attn_bf = P @ V  per (b,h), bf16 out ------------------
__global__ __launch_bounds__(256) void pv_kernel(
    const float* __restrict__ S, const float* __restrict__ qkv,
    bf16* __restrict__ attn_bf) {
  int bh = blockIdx.z;
  int b = bh / H_, h = bh % H_;
  int j0 = blockIdx.y * 64;
  int t = threadIdx.x;
  __shared__ float Ps[16][68];
  __shared__ float Vs[16][68];
  int tm = (t >> 4) << 2, tn = (t & 15) << 2;
  float acc[4][4] = {{0.f}};
  int lm = t >> 2;
  int lk = (t & 3) << 2;
  int vd = t & 63;
  int vk4 = (t >> 6) * 4;
  for (int k0 = 0; k0 < N_; k0 += 16) {
#pragma unroll
    for (int i = 0; i < 4; i++) {
      int kk = k0 + lk + i;
      float v = 0.f;
      if (j0 + lm < NT_ && kk < N_)
        v = S[((size_t)bh * NT_ + j0 + lm) * N_ + kk];
      Ps[lk + i][lm] = v;
    }
#pragma unroll
    for (int i = 0; i < 4; i++) {
      int kk = k0 + vk4 + i;
      float v = 0.f;
      if (kk < N_)
        v = qkv[(size_t)(b * N_ + kk) * QKVC + 2 * C_ + h * DH_ + vd];
      Vs[vk4 + i][vd] = v;
    }
    __syncthreads();
#pragma unroll
    for (int k = 0; k < 16; k++) {
      float a0 = Ps[k][tm + 0], a1 = Ps[k][tm + 1], a2 = Ps[k][tm + 2], a3 = Ps[k][tm + 3];
      float b0 = Vs[k][tn + 0], b1 = Vs[k][tn + 1], b2 = Vs[k][tn + 2], b3 = Vs[k][tn + 3];
      acc[0][0] += a0 * b0; acc[0][1] += a0 * b1; acc[0][2] += a0 * b2; acc[0][3] += a0 * b3;
      acc[1][0] += a1 * b0; acc[1][1] += a1 * b1; acc[1][2] += a1 * b2; acc[1][3] += a1 * b3;
      acc[2][0] += a2 * b0; acc[2][1] += a2 * b1; acc[2][2] += a2 * b2; acc[2][3] += a2 * b3;
      acc[3][0] += a3 * b0; acc[3][1] += a3 * b1; acc[3][2] += a3 * b2; acc[3][3] += a3 * b3;
    }
    __syncthreads();
  }
#pragma unroll
  for (int i = 0; i < 4; i++) {
    int m = j0 + tm + i;
    if (m >= NT_) continue;
#pragma unroll
    for (int jj = 0; jj < 4; jj++) {
      attn_bf[(size_t)(b * NT_ + m) * C_ + h * DH_ + tn + jj] =
          __float2bfloat16(acc[i][jj]);
    }
  }
}

// ---------------- epilogues ----------------
__global__ __launch_bounds__(256) void e2_kernel(
    const float* __restrict__ cbuf, const float* __restrict__ poln,
    const int* __restrict__ selidx, const float* __restrict__ x, float* __restrict__ x2) {
  int row = blockIdx.x;
  int t = threadIdx.x;
  int b = row / NT_;
  int r = selidx[row];
  float pn = poln[row];
  for (int i = t; i < C_; i += 256) {
    float sx = (r >= 0) ? x[(size_t)(b * N_ + r) * C_ + i] : 0.f;
    x2[(size_t)row * C_ + i] = sx + cbuf[(size_t)row * C_ + i] * pn;
  }
}

__global__ __launch_bounds__(256) void ln2_kernel(
    const float* __restrict__ xin, const float* __restrict__ w, const float* __restrict__ b,
    bf16* __restrict__ xoutb) {
  int row = blockIdx.x;
  int t = threadIdx.x;
  __shared__ float scr[8];
  const float* xr = xin + (size_t)row * C_;
  float vals[3];
#pragma unroll
  for (int i = 0; i < 3; i++) vals[i] = xr[t + i * 256];
  float s = vals[0] + vals[1] + vals[2];
  s = blockReduceSumF(s, scr, 4);
  float mean = s / (float)C_;
  float vs = 0.f;
#pragma unroll
  for (int i = 0; i < 3; i++) { float d = vals[i] - mean; vs += d * d; }
  vs = blockReduceSumF(vs, scr, 4);
  float sd = sqrtf(vs / (float)C_ + 1e-5f);
#pragma unroll
  for (int i = 0; i < 3; i++) {
    int c = t + i * 256;
    xoutb[(size_t)row * C_ + c] =
        __float2bfloat16((vals[i] - mean) / sd * w[c] + b[c]);
  }
}

DEV float gelu_exact(float v) { return 0.5f * v * (1.0f + erff(v * 0.70710678118654752f)); }

__global__ __launch_bounds__(256) void gelu_kernel(
    const float* __restrict__ h, bf16* __restrict__ hb) {
  size_t i = (size_t)blockIdx.x * 256 + threadIdx.x;
  float4 v = ((const float4*)h)[i];
  ushort4 o;
  o.x = __hip_bfloat16_raw(__float2bfloat16(gelu_exact(v.x))).x;
  o.y = __hip_bfloat16_raw(__float2bfloat16(gelu_exact(v.y))).x;
  o.z = __hip_bfloat16_raw(__float2bfloat16(gelu_exact(v.z))).x;
  o.w = __hip_bfloat16_raw(__float2bfloat16(gelu_exact(v.w))).x;
  ((ushort4*)hb)[i] = o;
}

__global__ __launch_bounds__(256) void e4_kernel(
    const float* __restrict__ x2, const float* __restrict__ cbuf,
    const float* __restrict__ poln, float* __restrict__ out) {
  int row = blockIdx.x;
  int t = threadIdx.x;
  float pn = poln[row];
  for (int i = t; i < C_; i += 256) {
    float v = x2[(size_t)row * C_ + i] + cbuf[(size_t)row * C_ + i] * pn;
    out[(size_t)row * C_ + i] = v;
  }
}

// ---------------- launcher ----------------
extern "C" void kernel_launch(void* const* d_in, const int* in_sizes, int n_in,
                              void* d_out, int out_size, void* d_ws, size_t ws_size,
                              hipStream_t stream) {
  const float* x      = (const float*)d_in[0];
  const float* policy = (const float*)d_in[1];
  const float* n1w    = (const float*)d_in[2];
  const float* n1b    = (const float*)d_in[3];
  const float* qkvw   = (const float*)d_in[4];
  const float* projw  = (const float*)d_in[5];
  const float* projb  = (const float*)d_in[6];
  const float* n2w    = (const float*)d_in[7];
  const float* n2b    = (const float*)d_in[8];
  const float* fc1w   = (const float*)d_in[9];
  const float* fc1b   = (const float*)d_in[10];
  const float* fc2w   = (const float*)d_in[11];
  const float* fc2b   = (const float*)d_in[12];

  char* ws = (char*)d_ws;
  size_t off = 0;
  auto alloc = [&](size_t bytes) {
    size_t o = off;
    off += (bytes + 255) & ~(size_t)255;
    return o;
  };

  double* xn64    = (double*)(ws + alloc((size_t)BN * C_ * 8));
  bf16*   xnb     = (bf16*)(ws + alloc((size_t)BN * C_ * 2));
  float*  qkv32   = (float*)(ws + alloc((size_t)BN * QKVC * 4));
  double* vnorm2  = (double*)(ws + alloc((size_t)BN * 8));
  double* q064    = (double*)(ws + alloc((size_t)B_ * C_ * 8));
  double* g64     = (double*)(ws + alloc((size_t)B_ * H_ * C_ * 8));
  double* l64     = (double*)(ws + alloc((size_t)B_ * H_ * N_ * 8));
  int*    selidx  = (int*)(ws + alloc((size_t)BT * 4));
  float*  poln    = (float*)(ws + alloc((size_t)BT * 4));
  bf16*   attn_bf = (bf16*)(ws + alloc((size_t)BT * C_ * 2));
  float*  cbuf    = (float*)(ws + alloc((size_t)BT * C_ * 4));
  float*  x2      = (float*)(ws + alloc((size_t)BT * C_ * 4));
  bf16*   qkvw_t  = (bf16*)(ws + alloc((size_t)QKVC * C_ * 2));
  bf16*   projw_t = (bf16*)(ws + alloc((size_t)C_ * C_ * 2));
  bf16*   fc1w_t  = (bf16*)(ws + alloc((size_t)4 * C_ * C_ * 2));
  bf16*   fc2w_t  = (bf16*)(ws + alloc((size_t)C_ * 4 * C_ * 2));

  // UNION: Sbuf (dead after pv) overlaps xn2_bf + h32 + h_bf (written after pv).
  size_t S_bytes    = (size_t)B_ * H_ * NT_ * N_ * 4;
  size_t xn2b_bytes = ((size_t)BT * C_ * 2 + 255) & ~(size_t)255;
  size_t h32_bytes  = ((size_t)BT * 4 * C_ * 4 + 255) & ~(size_t)255;
  size_t hbf_bytes  = (size_t)BT * 4 * C_ * 2;
  size_t late_bytes = xn2b_bytes + h32_bytes + hbf_bytes;
  size_t union_bytes = S_bytes > late_bytes ? S_bytes : late_bytes;
  char* ub    = ws + alloc(union_bytes);
  float* Sbuf  = (float*)ub;
  bf16*  xn2b  = (bf16*)ub;
  float* h32   = (float*)(ub + xn2b_bytes);
  bf16*  h_bf  = (bf16*)(ub + xn2b_bytes + h32_bytes);
  if (off > ws_size) return;

  float* out_x = (float*)d_out;
  float* out_p = out_x + (size_t)BT * C_;

  transpose_bf16<<<dim3(QKVC / 32, C_ / 32), 256, 0, stream>>>(qkvw, qkvw_t, C_, QKVC);
  transpose_bf16<<<dim3(C_ / 32, C_ / 32), 256, 0, stream>>>(projw, projw_t, C_, C_);
  transpose_bf16<<<dim3(4 * C_ / 32, C_ / 32), 256, 0, stream>>>(fc1w, fc1w_t, C_, 4 * C_);
  transpose_bf16<<<dim3(C_ / 32, 4 * C_ / 32), 256, 0, stream>>>(fc2w, fc2w_t, 4 * C_, C_);

  ln1_kernel<<<BN, 256, 0, stream>>>(x, n1w, n1b, xn64, xnb);

  {
    dim3 g(QKVC / 64, (BN + 63) / 64);
    gemm_bf16<<<g, 256, 0, stream>>>(xnb, qkvw_t, qkv32, nullptr, policy, BN, C_, QKVC);
  }

  // fp64 scoring path
  q0_kernel<<<B_, 256, 0, stream>>>(xn64, qkvw, policy, q064);
  g_kernel<<<B_ * H_, 256, 0, stream>>>(q064, qkvw, g64);
  logits_kernel<<<BN, 256, 0, stream>>>(xn64, g64, policy, l64);
  vnorm_kernel<<<BN / 4, 256, 0, stream>>>(xn64, qkvw, policy, vnorm2);
  softmax0_kernel<<<B_ * H_, 256, 0, stream>>>(l64, policy);
  select_kernel<<<B_, 1024, 0, stream>>>(l64, vnorm2, selidx, poln, out_p);

  // attention
  {
    dim3 g((N_ + 63) / 64, (NT_ + 63) / 64, B_ * H_);
    qk_kernel<<<g, 256, 0, stream>>>(qkv32, selidx, Sbuf);
  }
  smax_kernel<<<B_ * H_ * NT_, 256, 0, stream>>>(Sbuf, selidx, policy);
  {
    dim3 g(1, (NT_ + 63) / 64, B_ * H_);
    pv_kernel<<<g, 256, 0, stream>>>(Sbuf, qkv32, attn_bf);
  }

  {
    dim3 g(C_ / 64, (BT + 63) / 64);
    gemm_bf16<<<g, 256, 0, stream>>>(attn_bf, projw_t, cbuf, projb, nullptr, BT, C_, C_);
  }
  e2_kernel<<<BT, 256, 0, stream>>>(cbuf, poln, selidx, x, x2);
  ln2_kernel<<<BT, 256, 0, stream>>>(x2, n2w, n2b, xn2b);
  {
    dim3 g(4 * C_ / 64, (BT + 63) / 64);
    gemm_bf16<<<g, 256, 0, stream>>>(xn2b, fc1w_t, h32, fc1b, nullptr, BT, C_, 4 * C_);
  }
  gelu_kernel<<<(BT * 4 * C_) / 1024, 256, 0, stream>>>(h32, h_bf);
  {
    dim3 g(C_ / 64, (BT + 63) / 64);
    gemm_bf16<<<g, 256, 0, stream>>>(h_bf, fc2w_t, cbuf, fc2b, nullptr, BT, 4 * C_, C_);
  }
  e4_kernel<<<BT, 256, 0, stream>>>(x2, cbuf, poln, out_x);
}